// Round 2
// baseline (595.466 us; speedup 1.0000x reference)
//
#include <hip/hip_runtime.h>
#include <hip/hip_bf16.h>

// GCN: h1 = relu(Agg(x@W1)+b1); h2 = relu(Agg(h1@W2)+b2); out = mean(h2)@Wc + bc
// Agg via CSR gather; g = (X@W)*dinv stored OCP fp8 e4m3, PLANE-MAJOR:
//   gbuf[plane][node][32feats], plane = 3.2MB < 4MB per-XCD L2.
// agg_planes pins plane p to XCD pair {2p,2p+1} via blockIdx&7 (round-robin
// dispatch; verified r1: FETCH dropped 89.6->37.9MB). r1 lesson: 4 nodes/wave
// made loop bounds lane-divergent -> max-of-4 slot inflation x1.73 (113us).
// Now: ONE (node,plane) per wave, 4 edges of the SAME node per instruction
// (16-lane groups), wave-uniform bounds, packed fx2 accumulation, shfl reduce.
// csr/cursor/cnt/output traffic nontemporal to protect the plane in L2.
// CSR build atomic-free; ALL build kernels >= 391 blocks (r11: narrow build
// kernels were width-starved, ~270us invisible tail).
// GEMMs: mfma_f32_16x16x32_bf16, LDS-free, W pre-packed to k-block layout.

#define FEAT 128
#define CHUNK 4096      // edges per chunk (391 chunks)
#define MAXBUCK 512     // max node-buckets (N <= 131072); also NC cap
#define ECAP 12288      // LDS edge staging cap in bucket_scat (48 KB of int)

typedef __attribute__((ext_vector_type(8))) short short8;
typedef __attribute__((ext_vector_type(4))) float float4v;
typedef __attribute__((ext_vector_type(2))) float floatx2;

union I4S8 { int4 i; short8 s; };

static __device__ inline unsigned short f2bf(float f) {
    union { __hip_bfloat16 h; unsigned short u; } cv;
    cv.h = __float2bfloat16(f);
    return cv.u;
}

// ---- OCP fp8 e4m3 helpers ----
static __device__ inline floatx2 fp8x2_dec(unsigned int u) {
#if __has_builtin(__builtin_amdgcn_cvt_pk_f32_fp8)
    return __builtin_amdgcn_cvt_pk_f32_fp8((int)u, false);
#else
    floatx2 r;
    unsigned int b0 = u & 0xFFu, b1 = (u >> 8) & 0xFFu;
    r.x = __uint_as_float(((b0 & 0x80u) << 24) | ((b0 & 0x7Fu) << 20)) * 0x1p+120f;
    r.y = __uint_as_float(((b1 & 0x80u) << 24) | ((b1 & 0x7Fu) << 20)) * 0x1p+120f;
    return r;
#endif
}

static __device__ inline unsigned char fp8enc(float f) {
#if __has_builtin(__builtin_amdgcn_cvt_pk_fp8_f32)
    return (unsigned char)(__builtin_amdgcn_cvt_pk_fp8_f32(f, 0.0f, 0, false) & 0xFF);
#else
    unsigned int u = __float_as_uint(f);
    unsigned int s = (u >> 24) & 0x80u;
    float a = fabsf(f);
    a = fminf(a, 448.0f);
    unsigned int code;
    if (a < 0.015625f) {
        code = (unsigned int)(int)rintf(a * 512.0f);
    } else {
        unsigned int au = __float_as_uint(a);
        unsigned int r = au + 0x0007FFFFu + ((au >> 20) & 1u);
        unsigned int e = (r >> 23) - 120u;
        unsigned int m = (r >> 20) & 7u;
        code = (e << 3) | m;
        if (code > 0x7Eu) code = 0x7Eu;
    }
    return (unsigned char)(code | s);
#endif
}

// ---- build phase 1: per-chunk histogram over node buckets (dst>>8) ----
__global__ __launch_bounds__(256) void hist2(const int* __restrict__ dst,
                                             int* __restrict__ hist,
                                             int nE, int NC, int nbuck) {
    __shared__ int h[MAXBUCK];
    int c = blockIdx.x, t = threadIdx.x;
    for (int i = t; i < nbuck; i += 256) h[i] = 0;
    __syncthreads();
    int beg = c * CHUNK, end = min(nE, beg + CHUNK);
    for (int e = beg + t; e < end; e += 256)
        atomicAdd(&h[dst[e] >> 8], 1);
    __syncthreads();
    for (int i = t; i < nbuck; i += 256) hist[i * NC + c] = h[i];
}

// ---- phase 2a: per-bucket totals (wide: one block per bucket) ----
__global__ __launch_bounds__(256) void rowsum_k(const int* __restrict__ hist,
                                                int* __restrict__ btot, int NC) {
    __shared__ int red[256];
    int b = blockIdx.x, t = threadIdx.x;
    int s = 0;
    for (int c = t; c < NC; c += 256) s += hist[b * NC + c];
    red[t] = s;
    __syncthreads();
    for (int o = 128; o > 0; o >>= 1) {
        if (t < o) red[t] += red[t + o];
        __syncthreads();
    }
    if (t == 0) btot[b] = red[0];
}

// ---- phase 2b: exclusive scan of bucket totals (nbuck <= 512) ----
__global__ __launch_bounds__(512) void bscan_k(const int* __restrict__ btot,
                                               int* __restrict__ bboff, int nbuck) {
    __shared__ int sc[512];
    int t = threadIdx.x;
    int v = (t < nbuck) ? btot[t] : 0;
    sc[t] = v;
    __syncthreads();
    for (int o = 1; o < 512; o <<= 1) {
        int add = (t >= o) ? sc[t - o] : 0;
        __syncthreads();
        sc[t] += add;
        __syncthreads();
    }
    if (t < nbuck) {
        bboff[t] = sc[t] - v;
        if (t == nbuck - 1) bboff[nbuck] = sc[t];
    }
}

// ---- phase 2c: per-(bucket,chunk) offsets (wide: block-parallel scan, NC<=512) ----
__global__ __launch_bounds__(512) void rowoff_k(const int* __restrict__ hist,
                                                const int* __restrict__ bboff,
                                                int* __restrict__ hoff, int NC) {
    __shared__ int sc[512];
    int b = blockIdx.x, t = threadIdx.x;
    int v = (t < NC) ? hist[b * NC + t] : 0;
    sc[t] = v;
    __syncthreads();
    for (int o = 1; o < 512; o <<= 1) {
        int add = (t >= o) ? sc[t - o] : 0;
        __syncthreads();
        sc[t] += add;
        __syncthreads();
    }
    if (t < NC) hoff[b * NC + t] = bboff[b] + sc[t] - v;
}

// ---- phase 3: pack (src<<8|dloc) bucket-grouped; LDS cursors ----
__global__ __launch_bounds__(256) void fill2(const int* __restrict__ src,
                                             const int* __restrict__ dst,
                                             const int* __restrict__ off,
                                             int* __restrict__ binned,
                                             int nE, int NC, int nbuck) {
    __shared__ int cur[MAXBUCK];
    int c = blockIdx.x, t = threadIdx.x;
    for (int i = t; i < nbuck; i += 256) cur[i] = off[i * NC + c];
    __syncthreads();
    int beg = c * CHUNK, end = min(nE, beg + CHUNK);
    for (int e = beg + t; e < end; e += 256) {
        int d = dst[e];
        int pos = atomicAdd(&cur[d >> 8], 1);
        binned[pos] = (src[e] << 8) | (d & 255);
    }
}

// ---- phase 4: per-bucket count + dinv + cursor + csr scatter (all LDS) ----
__global__ __launch_bounds__(256) void bucket_scat(const int* __restrict__ binned,
                                                   const int* __restrict__ bboff,
                                                   int* __restrict__ cnt,
                                                   float* __restrict__ dinv,
                                                   int* __restrict__ cursor,
                                                   int* __restrict__ csr_src, int n) {
    __shared__ int se[ECAP];
    __shared__ int lcnt[256];
    __shared__ int lcur[256];
    __shared__ int ssc[256];
    int b = blockIdx.x, t = threadIdx.x;
    int node0 = b << 8;
    int nloc = min(256, n - node0);
    int ebeg = bboff[b], eend = bboff[b + 1];
    int ne = eend - ebeg;
    lcnt[t] = 0;
    __syncthreads();
    bool staged = (ne <= ECAP);
    if (staged) {
        for (int i = t; i < ne; i += 256) {
            int e = binned[ebeg + i];
            se[i] = e;
            atomicAdd(&lcnt[e & 255], 1);
        }
    } else {
        for (int i = t; i < ne; i += 256)
            atomicAdd(&lcnt[binned[ebeg + i] & 255], 1);
    }
    __syncthreads();
    int myc = (t < nloc) ? lcnt[t] : 0;
    ssc[t] = myc;
    __syncthreads();
    for (int o = 1; o < 256; o <<= 1) {
        int add = (t >= o) ? ssc[t - o] : 0;
        __syncthreads();
        ssc[t] += add;
        __syncthreads();
    }
    int excl = ssc[t] - myc;
    if (t < nloc) {
        cnt[node0 + t] = myc;
        dinv[node0 + t] = rsqrtf((float)(myc + 1));
        cursor[node0 + t] = ebeg + excl;   // cursor = start of node's list
        lcur[t] = excl;
    }
    __syncthreads();
    if (staged) {
        for (int i = t; i < ne; i += 256) {
            int e = se[i];
            int pos = atomicAdd(&lcur[e & 255], 1);
            csr_src[ebeg + pos] = ((unsigned int)e) >> 8;
        }
    } else {
        for (int i = t; i < ne; i += 256) {
            int e = binned[ebeg + i];
            int pos = atomicAdd(&lcur[e & 255], 1);
            csr_src[ebeg + pos] = ((unsigned int)e) >> 8;
        }
    }
}

// ---- W pre-pack (both layers) + pooled zero-init ----
__global__ __launch_bounds__(256) void wprep2(const float* __restrict__ W1,
                                              const float* __restrict__ W2,
                                              unsigned short* __restrict__ Wbf1,
                                              unsigned short* __restrict__ Wbf2,
                                              float* __restrict__ pooled) {
    int tid = blockIdx.x * 256 + threadIdx.x;   // 32768 threads
    if (tid < FEAT) pooled[tid] = 0.0f;
    const float* W = (tid < 16384) ? W1 : W2;
    unsigned short* O = (tid < 16384) ? Wbf1 : Wbf2;
    int id = tid & 16383;
    int chunk = id >> 3, j = id & 7;
    int kb = chunk >> 7, nn = chunk & 127;
    O[id] = f2bf(W[(kb * 8 + j) * FEAT + nn]);
}

// ---- MFMA GEMM: gout[plane][N][32](fp8) = bf16(X) @ Wbf * dinv[row] ----
// plane-major output: plane = col>>5, 32 fp8 feats per node per plane.
template <bool AFP32>
__global__ __launch_bounds__(256) void gemm_mfma(const void* __restrict__ Xv,
                                                 const unsigned short* __restrict__ Wbf,
                                                 const float* __restrict__ dinv,
                                                 unsigned char* __restrict__ gout,
                                                 int n) {
    int wave = threadIdx.x >> 6, lane = threadIdx.x & 63;
    int m0 = blockIdx.x * 64 + wave * 16;
    if (m0 >= n) return;
    int col = lane & 15, quad = lane >> 4;
    int mc = min(m0 + col, n - 1);

    short8 afr[4];
    if (AFP32) {
        const float* X = (const float*)Xv;
        const float* xr = X + (size_t)mc * FEAT + quad * 8;
#pragma unroll
        for (int ks = 0; ks < 4; ks++) {
            float4 lo = *(const float4*)(xr + ks * 32);
            float4 hi = *(const float4*)(xr + ks * 32 + 4);
            short8 a;
            a[0] = (short)f2bf(lo.x); a[1] = (short)f2bf(lo.y);
            a[2] = (short)f2bf(lo.z); a[3] = (short)f2bf(lo.w);
            a[4] = (short)f2bf(hi.x); a[5] = (short)f2bf(hi.y);
            a[6] = (short)f2bf(hi.z); a[7] = (short)f2bf(hi.w);
            afr[ks] = a;
        }
    } else {
        const int4* X = (const int4*)Xv;
        const int4* xr = X + (size_t)mc * (FEAT / 8) + quad;
#pragma unroll
        for (int ks = 0; ks < 4; ks++) {
            I4S8 u; u.i = xr[ks * 4];
            afr[ks] = u.s;
        }
    }

    float dvr[4];
#pragma unroll
    for (int r = 0; r < 4; r++)
        dvr[r] = dinv[min(m0 + quad * 4 + r, n - 1)];

    const int4* Wb = (const int4*)Wbf;
#pragma unroll
    for (int nt = 0; nt < 8; nt++) {
        float4v acc = {0.f, 0.f, 0.f, 0.f};
#pragma unroll
        for (int ks = 0; ks < 4; ks++) {
            int kb = ks * 4 + quad;
            I4S8 u; u.i = Wb[kb * FEAT + nt * 16 + col];
            acc = __builtin_amdgcn_mfma_f32_16x16x32_bf16(afr[ks], u.s, acc, 0, 0, 0);
        }
        int pl = nt >> 1;                       // feature plane 0..3
        int wi = ((nt & 1) << 4) | col;         // offset within 32-feat plane
#pragma unroll
        for (int r = 0; r < 4; r++) {
            int row = m0 + quad * 4 + r;
            if (row < n)
                gout[((size_t)pl * n + row) * 32 + wi] = fp8enc(acc[r] * dvr[r]);
        }
    }
}

// ---- agg: XCD-pinned feature-plane CSR gather + bias + relu -> bf16 rows ----
// block b: xcd = b&7 (round-robin dispatch), plane = xcd>>1, half = xcd&1.
// Per-XCD gather working set = one 3.2MB plane -> L2-resident.
// Wave = ONE (node,plane) at a time (wave-uniform loop bounds, r1 lesson);
// 4 edges of that node per instruction via the four 16-lane groups.
// Each wave serially covers 4 nodes; 16 nodes per block.
__global__ __launch_bounds__(256) void agg_planes(const int* __restrict__ cursor,
                                                  const int* __restrict__ cnt,
                                                  const int* __restrict__ csr_src,
                                                  const unsigned short* __restrict__ gs,
                                                  const float* __restrict__ dinv,
                                                  const float* __restrict__ bias,
                                                  unsigned int* __restrict__ outb,
                                                  int n, int Nh) {
    int b = blockIdx.x;
    int xcd = b & 7;
    int plane = xcd >> 1, half = xcd & 1;
    int wave = threadIdx.x >> 6, lane = threadIdx.x & 63;
    int fp = lane & 15;          // feature-pair within 32-feat plane
    int g = lane >> 4;           // edge sub-slot 0..3
    int node0 = half * Nh + ((b >> 3) * 4 + wave) * 4;
    int nodeLim = min(n, (half + 1) * Nh);

    const unsigned short* gp = gs + (size_t)plane * ((size_t)n * 16);
    float2 bv = ((const float2*)bias)[plane * 16 + fp];

#pragma unroll 1
    for (int i = 0; i < 4; i++) {
        int node = node0 + i;
        if (node >= nodeLim) break;                 // wave-uniform
        int beg = __builtin_nontemporal_load(&cursor[node]);
        int ne  = __builtin_nontemporal_load(&cnt[node]);
        int end = beg + ne;

        floatx2 ax0 = {0.f, 0.f}, ax1 = {0.f, 0.f};
        floatx2 ax2 = {0.f, 0.f}, ax3 = {0.f, 0.f};
        if (g == 0)
            ax0 = fp8x2_dec(gp[(size_t)node * 16 + fp]);   // self-loop

        int j = beg;
        // main: 16 edges per iter (4 sub-steps x 4 groups), uniform bounds
        for (; j + 15 < end; j += 16) {
            int s0 = __builtin_nontemporal_load(&csr_src[j + g]);
            int s1 = __builtin_nontemporal_load(&csr_src[j + 4 + g]);
            int s2 = __builtin_nontemporal_load(&csr_src[j + 8 + g]);
            int s3 = __builtin_nontemporal_load(&csr_src[j + 12 + g]);
            unsigned int u0 = gp[(size_t)s0 * 16 + fp];
            unsigned int u1 = gp[(size_t)s1 * 16 + fp];
            unsigned int u2 = gp[(size_t)s2 * 16 + fp];
            unsigned int u3 = gp[(size_t)s3 * 16 + fp];
            ax0 += fp8x2_dec(u0);
            ax1 += fp8x2_dec(u1);
            ax2 += fp8x2_dec(u2);
            ax3 += fp8x2_dec(u3);
        }
        // tail: 4 edges per iter
        for (; j + 3 < end; j += 4) {
            int s0 = __builtin_nontemporal_load(&csr_src[j + g]);
            ax1 += fp8x2_dec(gp[(size_t)s0 * 16 + fp]);
        }
        // remainder (<4): groups with j+g < end active (masked)
        if (j + g < end) {
            int s0 = __builtin_nontemporal_load(&csr_src[j + g]);
            ax2 += fp8x2_dec(gp[(size_t)s0 * 16 + fp]);
        }

        floatx2 a = (ax0 + ax1) + (ax2 + ax3);
        // reduce across the 4 groups (lanes l, l^16, l^32, l^48)
        a.x += __shfl_xor(a.x, 16);
        a.y += __shfl_xor(a.y, 16);
        a.x += __shfl_xor(a.x, 32);
        a.y += __shfl_xor(a.y, 32);

        if (g == 0) {
            float dv = dinv[node];
            float2 r;
            r.x = fmaxf(a.x * dv + bv.x, 0.0f);
            r.y = fmaxf(a.y * dv + bv.y, 0.0f);
            union { __hip_bfloat162 h; unsigned int u; } cv;
            cv.h = __float22bfloat162_rn(r);
            __builtin_nontemporal_store(cv.u, &outb[(size_t)node * 64 + plane * 16 + fp]);
        }
    }
}

// ---- mean pool stage 1 (bf16 input, 1024 blocks) ----
__global__ __launch_bounds__(256) void pool_kernel(const __hip_bfloat16* __restrict__ a,
                                                   float* __restrict__ pooled, int n) {
    int tid = blockIdx.x * 256 + threadIdx.x;  // 1024 blocks -> 262144 threads
    int f = tid & 127;
    int i0 = tid >> 7;  // 0..2047
    float s = 0.0f;
    for (int i = i0; i < n; i += 2048) s += __bfloat162float(a[(size_t)i * FEAT + f]);
    atomicAdd(&pooled[f], s);
}

// ---- final: out[c] = (pooled/N) . Wc[:,c] + bc[c] ----
__global__ __launch_bounds__(128) void final_kernel(const float* __restrict__ pooled,
                                                    const float* __restrict__ Wc,
                                                    const float* __restrict__ bc,
                                                    float* __restrict__ out,
                                                    int n, int C) {
    __shared__ float p[FEAT];
    int t = threadIdx.x;
    p[t] = pooled[t] * (1.0f / (float)n);
    __syncthreads();
    if (t < C) {
        float acc = bc[t];
        for (int h = 0; h < FEAT; h++)
            acc += p[h] * Wc[h * C + t];
        out[t] = acc;
    }
}

extern "C" void kernel_launch(void* const* d_in, const int* in_sizes, int n_in,
                              void* d_out, int out_size, void* d_ws, size_t ws_size,
                              hipStream_t stream) {
    const float* x  = (const float*)d_in[0];
    const int*   ei = (const int*)d_in[1];
    const float* W1 = (const float*)d_in[2];
    const float* b1 = (const float*)d_in[3];
    const float* W2 = (const float*)d_in[4];
    const float* b2 = (const float*)d_in[5];
    const float* Wc = (const float*)d_in[6];
    const float* bc = (const float*)d_in[7];

    const int N = in_sizes[0] / FEAT;        // 100000
    const int E = in_sizes[1] / 2;           // 1600000
    const int C = out_size;                  // 32
    const int* srcI = ei;
    const int* dstI = ei + E;
    const int NC = (E + CHUNK - 1) / CHUNK;  // edge chunks (391, <= 512)
    const int NBK = (N + 255) >> 8;          // node buckets (391, <= MAXBUCK)

    // workspace carve (256B aligned)
    auto align256 = [](size_t v) { return (v + 255) & ~(size_t)255; };
    char* w = (char*)d_ws;
    int*            cnt     = (int*)w;            w += align256((size_t)N * 4);
    float*          dinv    = (float*)w;          w += align256((size_t)N * 4);
    int*            cursor  = (int*)w;            w += align256((size_t)N * 4);
    int*            csr_src = (int*)w;            w += align256((size_t)E * 4);
    int*            binned  = (int*)w;            w += align256((size_t)E * 4);
    int*            hist    = (int*)w;            w += align256((size_t)NBK * NC * 4);
    int*            hoff    = (int*)w;            w += align256((size_t)NBK * NC * 4);
    int*            btot    = (int*)w;            w += align256((size_t)NBK * 4);
    int*            bboff   = (int*)w;            w += align256((size_t)(NBK + 1) * 4);
    unsigned short* Wbf1    = (unsigned short*)w; w += align256((size_t)FEAT * FEAT * 2);
    unsigned short* Wbf2    = (unsigned short*)w; w += align256((size_t)FEAT * FEAT * 2);
    unsigned char*  gbuf    = (unsigned char*)w;  w += align256((size_t)N * FEAT);
    unsigned short* bufA    = (unsigned short*)w; w += align256((size_t)N * FEAT * 2);
    float*          pooled  = (float*)w;          w += align256((size_t)FEAT * 4);

    // W pre-pack (both layers) + pooled zero
    wprep2<<<128, 256, 0, stream>>>(W1, W2, Wbf1, Wbf2, pooled);

    // ---- atomic-free CSR build (all kernels >= 391 blocks except bscan) ----
    hist2<<<NC, 256, 0, stream>>>(dstI, hist, E, NC, NBK);
    rowsum_k<<<NBK, 256, 0, stream>>>(hist, btot, NC);
    bscan_k<<<1, 512, 0, stream>>>(btot, bboff, NBK);
    rowoff_k<<<NBK, 512, 0, stream>>>(hist, bboff, hoff, NC);
    fill2<<<NC, 256, 0, stream>>>(srcI, dstI, hoff, binned, E, NC, NBK);
    bucket_scat<<<NBK, 256, 0, stream>>>(binned, bboff, cnt, dinv, cursor, csr_src, N);

    const int gGemm = (N + 63) / 64;
    const int Nh = (N + 1) >> 1;             // nodes per half
    const int gAgg = ((Nh + 15) / 16) * 8;   // 8 XCD-pinned lanes of blocks

    // ---- layer 1 ----
    gemm_mfma<true><<<gGemm, 256, 0, stream>>>(x, Wbf1, dinv, gbuf, N);
    agg_planes<<<gAgg, 256, 0, stream>>>(cursor, cnt, csr_src,
                                         (const unsigned short*)gbuf, dinv, b1,
                                         (unsigned int*)bufA, N, Nh);

    // ---- layer 2 ----
    gemm_mfma<false><<<gGemm, 256, 0, stream>>>(bufA, Wbf2, dinv, gbuf, N);
    agg_planes<<<gAgg, 256, 0, stream>>>(cursor, cnt, csr_src,
                                         (const unsigned short*)gbuf, dinv, b2,
                                         (unsigned int*)bufA, N, Nh);

    // ---- pool + classifier ----
    pool_kernel<<<1024, 256, 0, stream>>>((const __hip_bfloat16*)bufA, pooled, N);
    final_kernel<<<1, 128, 0, stream>>>(pooled, Wc, bc, (float*)d_out, N, C);
}

// Round 3
// 453.073 us; speedup vs baseline: 1.3143x; 1.3143x over previous
//
#include <hip/hip_runtime.h>
#include <hip/hip_bf16.h>

// GCN: h1 = relu(Agg(x@W1)+b1); h2 = relu(Agg(h1@W2)+b2); out = mean(h2)@Wc + bc
// Agg via CSR gather; g = (X@W)*dinv stored OCP fp8 e4m3, PLANE-MAJOR:
//   gbuf[plane][node][32feats], plane = 3.2MB < 4MB per-XCD L2.
// agg_planes pins plane p to XCD pair {2p,2p+1} via blockIdx&7 (round-robin
// dispatch; verified r1: FETCH dropped 89.6->37.9MB).
// r1 lesson: 4 nodes/wave with UNMATCHED degrees -> max-of-4 slot inflation
// x1.73 (113us). r2 lesson: uniform bounds via serial per-node chains killed
// MLP (4-deep, 173us). Fix: r1 structure (per-group independent 16-deep
// pipelines, 128B/gather-instr) + DEGREE-MATCHED groups via perm[]:
// bucket_scat counting-sorts each 256-node bucket by degree in LDS (free).
// csr/idx traffic nontemporal to protect the plane in L2.
// CSR build atomic-free; ALL build kernels >= 391 blocks (r11: narrow build
// kernels were width-starved, ~270us invisible tail).
// GEMMs: mfma_f32_16x16x32_bf16, LDS-free, W pre-packed to k-block layout.

#define FEAT 128
#define CHUNK 4096      // edges per chunk (391 chunks)
#define MAXBUCK 512     // max node-buckets (N <= 131072); also NC cap
#define ECAP 12288      // LDS edge staging cap in bucket_scat (48 KB of int)

typedef __attribute__((ext_vector_type(8))) short short8;
typedef __attribute__((ext_vector_type(4))) float float4v;
typedef __attribute__((ext_vector_type(2))) float floatx2;

union I4S8 { int4 i; short8 s; };

static __device__ inline unsigned short f2bf(float f) {
    union { __hip_bfloat16 h; unsigned short u; } cv;
    cv.h = __float2bfloat16(f);
    return cv.u;
}

// ---- OCP fp8 e4m3 helpers ----
static __device__ inline floatx2 fp8x2_dec(unsigned int u) {
#if __has_builtin(__builtin_amdgcn_cvt_pk_f32_fp8)
    return __builtin_amdgcn_cvt_pk_f32_fp8((int)u, false);
#else
    floatx2 r;
    unsigned int b0 = u & 0xFFu, b1 = (u >> 8) & 0xFFu;
    r.x = __uint_as_float(((b0 & 0x80u) << 24) | ((b0 & 0x7Fu) << 20)) * 0x1p+120f;
    r.y = __uint_as_float(((b1 & 0x80u) << 24) | ((b1 & 0x7Fu) << 20)) * 0x1p+120f;
    return r;
#endif
}

static __device__ inline unsigned char fp8enc(float f) {
#if __has_builtin(__builtin_amdgcn_cvt_pk_fp8_f32)
    return (unsigned char)(__builtin_amdgcn_cvt_pk_fp8_f32(f, 0.0f, 0, false) & 0xFF);
#else
    unsigned int u = __float_as_uint(f);
    unsigned int s = (u >> 24) & 0x80u;
    float a = fabsf(f);
    a = fminf(a, 448.0f);
    unsigned int code;
    if (a < 0.015625f) {
        code = (unsigned int)(int)rintf(a * 512.0f);
    } else {
        unsigned int au = __float_as_uint(a);
        unsigned int r = au + 0x0007FFFFu + ((au >> 20) & 1u);
        unsigned int e = (r >> 23) - 120u;
        unsigned int m = (r >> 20) & 7u;
        code = (e << 3) | m;
        if (code > 0x7Eu) code = 0x7Eu;
    }
    return (unsigned char)(code | s);
#endif
}

// ---- build phase 1: per-chunk histogram over node buckets (dst>>8) ----
__global__ __launch_bounds__(256) void hist2(const int* __restrict__ dst,
                                             int* __restrict__ hist,
                                             int nE, int NC, int nbuck) {
    __shared__ int h[MAXBUCK];
    int c = blockIdx.x, t = threadIdx.x;
    for (int i = t; i < nbuck; i += 256) h[i] = 0;
    __syncthreads();
    int beg = c * CHUNK, end = min(nE, beg + CHUNK);
    for (int e = beg + t; e < end; e += 256)
        atomicAdd(&h[dst[e] >> 8], 1);
    __syncthreads();
    for (int i = t; i < nbuck; i += 256) hist[i * NC + c] = h[i];
}

// ---- phase 2a: per-bucket totals (wide: one block per bucket) ----
__global__ __launch_bounds__(256) void rowsum_k(const int* __restrict__ hist,
                                                int* __restrict__ btot, int NC) {
    __shared__ int red[256];
    int b = blockIdx.x, t = threadIdx.x;
    int s = 0;
    for (int c = t; c < NC; c += 256) s += hist[b * NC + c];
    red[t] = s;
    __syncthreads();
    for (int o = 128; o > 0; o >>= 1) {
        if (t < o) red[t] += red[t + o];
        __syncthreads();
    }
    if (t == 0) btot[b] = red[0];
}

// ---- phase 2b: exclusive scan of bucket totals (nbuck <= 512) ----
__global__ __launch_bounds__(512) void bscan_k(const int* __restrict__ btot,
                                               int* __restrict__ bboff, int nbuck) {
    __shared__ int sc[512];
    int t = threadIdx.x;
    int v = (t < nbuck) ? btot[t] : 0;
    sc[t] = v;
    __syncthreads();
    for (int o = 1; o < 512; o <<= 1) {
        int add = (t >= o) ? sc[t - o] : 0;
        __syncthreads();
        sc[t] += add;
        __syncthreads();
    }
    if (t < nbuck) {
        bboff[t] = sc[t] - v;
        if (t == nbuck - 1) bboff[nbuck] = sc[t];
    }
}

// ---- phase 2c: per-(bucket,chunk) offsets (wide: block-parallel scan, NC<=512) ----
__global__ __launch_bounds__(512) void rowoff_k(const int* __restrict__ hist,
                                                const int* __restrict__ bboff,
                                                int* __restrict__ hoff, int NC) {
    __shared__ int sc[512];
    int b = blockIdx.x, t = threadIdx.x;
    int v = (t < NC) ? hist[b * NC + t] : 0;
    sc[t] = v;
    __syncthreads();
    for (int o = 1; o < 512; o <<= 1) {
        int add = (t >= o) ? sc[t - o] : 0;
        __syncthreads();
        sc[t] += add;
        __syncthreads();
    }
    if (t < NC) hoff[b * NC + t] = bboff[b] + sc[t] - v;
}

// ---- phase 3: pack (src<<8|dloc) bucket-grouped; LDS cursors ----
__global__ __launch_bounds__(256) void fill2(const int* __restrict__ src,
                                             const int* __restrict__ dst,
                                             const int* __restrict__ off,
                                             int* __restrict__ binned,
                                             int nE, int NC, int nbuck) {
    __shared__ int cur[MAXBUCK];
    int c = blockIdx.x, t = threadIdx.x;
    for (int i = t; i < nbuck; i += 256) cur[i] = off[i * NC + c];
    __syncthreads();
    int beg = c * CHUNK, end = min(nE, beg + CHUNK);
    for (int e = beg + t; e < end; e += 256) {
        int d = dst[e];
        int pos = atomicAdd(&cur[d >> 8], 1);
        binned[pos] = (src[e] << 8) | (d & 255);
    }
}

// ---- phase 4: per-bucket count + dinv + cursor + csr scatter (all LDS)
//      + degree-rank counting sort -> perm (degree-matched wave packing) ----
__global__ __launch_bounds__(256) void bucket_scat(const int* __restrict__ binned,
                                                   const int* __restrict__ bboff,
                                                   int* __restrict__ cnt,
                                                   float* __restrict__ dinv,
                                                   int* __restrict__ cursor,
                                                   int* __restrict__ csr_src,
                                                   int* __restrict__ perm, int n) {
    __shared__ int se[ECAP];
    __shared__ int lcnt[256];
    __shared__ int lcur[256];
    __shared__ int ssc[256];
    __shared__ int dbin[256];
    __shared__ int dcur[256];
    int b = blockIdx.x, t = threadIdx.x;
    int node0 = b << 8;
    int nloc = min(256, n - node0);
    int ebeg = bboff[b], eend = bboff[b + 1];
    int ne = eend - ebeg;
    lcnt[t] = 0;
    __syncthreads();
    bool staged = (ne <= ECAP);
    if (staged) {
        for (int i = t; i < ne; i += 256) {
            int e = binned[ebeg + i];
            se[i] = e;
            atomicAdd(&lcnt[e & 255], 1);
        }
    } else {
        for (int i = t; i < ne; i += 256)
            atomicAdd(&lcnt[binned[ebeg + i] & 255], 1);
    }
    __syncthreads();
    int myc = (t < nloc) ? lcnt[t] : 0;
    ssc[t] = myc;
    __syncthreads();
    for (int o = 1; o < 256; o <<= 1) {
        int add = (t >= o) ? ssc[t - o] : 0;
        __syncthreads();
        ssc[t] += add;
        __syncthreads();
    }
    int excl = ssc[t] - myc;
    if (t < nloc) {
        cnt[node0 + t] = myc;
        dinv[node0 + t] = rsqrtf((float)(myc + 1));
        cursor[node0 + t] = ebeg + excl;   // cursor = start of node's list
        lcur[t] = excl;
    }
    __syncthreads();
    if (staged) {
        for (int i = t; i < ne; i += 256) {
            int e = se[i];
            int pos = atomicAdd(&lcur[e & 255], 1);
            csr_src[ebeg + pos] = ((unsigned int)e) >> 8;
        }
    } else {
        for (int i = t; i < ne; i += 256) {
            int e = binned[ebeg + i];
            int pos = atomicAdd(&lcur[e & 255], 1);
            csr_src[ebeg + pos] = ((unsigned int)e) >> 8;
        }
    }
    // ---- degree-rank within bucket: counting sort -> perm[node0+rank]=node.
    // Real nodes bin at min(deg,254); pad threads bin at 255 so real ranks
    // stay in [0,nloc). 4 consecutive perm slots => near-equal degree.
    int degc = (t < nloc) ? min(myc, 254) : 255;
    dbin[t] = 0;
    __syncthreads();
    atomicAdd(&dbin[degc], 1);
    __syncthreads();
    int dv2 = dbin[t];
    for (int o = 1; o < 256; o <<= 1) {
        int add = (t >= o) ? dbin[t - o] : 0;
        __syncthreads();
        dbin[t] += add;
        __syncthreads();
    }
    dcur[t] = dbin[t] - dv2;   // exclusive bin offset
    __syncthreads();
    if (t < nloc) {
        int r = atomicAdd(&dcur[degc], 1);
        perm[node0 + r] = node0 + t;
    }
}

// ---- W pre-pack (both layers) + pooled zero-init ----
__global__ __launch_bounds__(256) void wprep2(const float* __restrict__ W1,
                                              const float* __restrict__ W2,
                                              unsigned short* __restrict__ Wbf1,
                                              unsigned short* __restrict__ Wbf2,
                                              float* __restrict__ pooled) {
    int tid = blockIdx.x * 256 + threadIdx.x;   // 32768 threads
    if (tid < FEAT) pooled[tid] = 0.0f;
    const float* W = (tid < 16384) ? W1 : W2;
    unsigned short* O = (tid < 16384) ? Wbf1 : Wbf2;
    int id = tid & 16383;
    int chunk = id >> 3, j = id & 7;
    int kb = chunk >> 7, nn = chunk & 127;
    O[id] = f2bf(W[(kb * 8 + j) * FEAT + nn]);
}

// ---- MFMA GEMM: gout[plane][N][32](fp8) = bf16(X) @ Wbf * dinv[row] ----
// plane-major output: plane = col>>5, 32 fp8 feats per node per plane.
template <bool AFP32>
__global__ __launch_bounds__(256) void gemm_mfma(const void* __restrict__ Xv,
                                                 const unsigned short* __restrict__ Wbf,
                                                 const float* __restrict__ dinv,
                                                 unsigned char* __restrict__ gout,
                                                 int n) {
    int wave = threadIdx.x >> 6, lane = threadIdx.x & 63;
    int m0 = blockIdx.x * 64 + wave * 16;
    if (m0 >= n) return;
    int col = lane & 15, quad = lane >> 4;
    int mc = min(m0 + col, n - 1);

    short8 afr[4];
    if (AFP32) {
        const float* X = (const float*)Xv;
        const float* xr = X + (size_t)mc * FEAT + quad * 8;
#pragma unroll
        for (int ks = 0; ks < 4; ks++) {
            float4 lo = *(const float4*)(xr + ks * 32);
            float4 hi = *(const float4*)(xr + ks * 32 + 4);
            short8 a;
            a[0] = (short)f2bf(lo.x); a[1] = (short)f2bf(lo.y);
            a[2] = (short)f2bf(lo.z); a[3] = (short)f2bf(lo.w);
            a[4] = (short)f2bf(hi.x); a[5] = (short)f2bf(hi.y);
            a[6] = (short)f2bf(hi.z); a[7] = (short)f2bf(hi.w);
            afr[ks] = a;
        }
    } else {
        const int4* X = (const int4*)Xv;
        const int4* xr = X + (size_t)mc * (FEAT / 8) + quad;
#pragma unroll
        for (int ks = 0; ks < 4; ks++) {
            I4S8 u; u.i = xr[ks * 4];
            afr[ks] = u.s;
        }
    }

    float dvr[4];
#pragma unroll
    for (int r = 0; r < 4; r++)
        dvr[r] = dinv[min(m0 + quad * 4 + r, n - 1)];

    const int4* Wb = (const int4*)Wbf;
#pragma unroll
    for (int nt = 0; nt < 8; nt++) {
        float4v acc = {0.f, 0.f, 0.f, 0.f};
#pragma unroll
        for (int ks = 0; ks < 4; ks++) {
            int kb = ks * 4 + quad;
            I4S8 u; u.i = Wb[kb * FEAT + nt * 16 + col];
            acc = __builtin_amdgcn_mfma_f32_16x16x32_bf16(afr[ks], u.s, acc, 0, 0, 0);
        }
        int pl = nt >> 1;                       // feature plane 0..3
        int wi = ((nt & 1) << 4) | col;         // offset within 32-feat plane
#pragma unroll
        for (int r = 0; r < 4; r++) {
            int row = m0 + quad * 4 + r;
            if (row < n)
                gout[((size_t)pl * n + row) * 32 + wi] = fp8enc(acc[r] * dvr[r]);
        }
    }
}

// ---- plane gather core: one node per 16-lane group, 2 fp8 feats/lane,
//      16-deep idx+gather pipeline (per-group independent bounds) ----
static __device__ inline void gather_plane(const int* __restrict__ csr_src,
                                           const unsigned short* __restrict__ gp,
                                           int beg, int end, int node, int fp,
                                           float& sx, float& sy) {
    floatx2 a0 = fp8x2_dec(gp[(size_t)node * 16 + fp]);   // self-loop term
    floatx2 a1 = {0.f, 0.f}, a2 = {0.f, 0.f}, a3 = {0.f, 0.f};
    int j = beg;
    for (; j + 15 < end; j += 16) {
        int sIdx[16];
#pragma unroll
        for (int k = 0; k < 16; k++) sIdx[k] = __builtin_nontemporal_load(&csr_src[j + k]);
        unsigned int uu[16];
#pragma unroll
        for (int k = 0; k < 16; k++) uu[k] = gp[(size_t)sIdx[k] * 16 + fp];
#pragma unroll
        for (int k = 0; k < 16; k += 4) {
            a0 += fp8x2_dec(uu[k]);
            a1 += fp8x2_dec(uu[k + 1]);
            a2 += fp8x2_dec(uu[k + 2]);
            a3 += fp8x2_dec(uu[k + 3]);
        }
    }
    for (; j + 3 < end; j += 4) {
        int s0 = __builtin_nontemporal_load(&csr_src[j]);
        int s1 = __builtin_nontemporal_load(&csr_src[j + 1]);
        int s2 = __builtin_nontemporal_load(&csr_src[j + 2]);
        int s3 = __builtin_nontemporal_load(&csr_src[j + 3]);
        a0 += fp8x2_dec(gp[(size_t)s0 * 16 + fp]);
        a1 += fp8x2_dec(gp[(size_t)s1 * 16 + fp]);
        a2 += fp8x2_dec(gp[(size_t)s2 * 16 + fp]);
        a3 += fp8x2_dec(gp[(size_t)s3 * 16 + fp]);
    }
    for (; j < end; j++) {
        int s0 = __builtin_nontemporal_load(&csr_src[j]);
        a0 += fp8x2_dec(gp[(size_t)s0 * 16 + fp]);
    }
    floatx2 a = (a0 + a1) + (a2 + a3);
    sx = a.x;
    sy = a.y;
}

// ---- agg: XCD-pinned feature-plane CSR gather + bias + relu -> bf16 rows ----
// block b: xcd = b&7 (round-robin dispatch), plane = xcd>>1, half = xcd&1.
// Per-XCD gather working set = one 3.2MB plane -> L2-resident.
// Wave = 4 (node,plane) tasks, one per 16-lane group, nodes via degree-sorted
// perm[] so the 4 groups have near-equal trip counts (no max-of-4 inflation).
__global__ __launch_bounds__(256) void agg_planes(const int* __restrict__ cursor,
                                                  const int* __restrict__ cnt,
                                                  const int* __restrict__ csr_src,
                                                  const unsigned short* __restrict__ gs,
                                                  const float* __restrict__ dinv,
                                                  const float* __restrict__ bias,
                                                  const int* __restrict__ perm,
                                                  unsigned int* __restrict__ outb,
                                                  int n, int Nh) {
    int b = blockIdx.x;
    int xcd = b & 7;
    int plane = xcd >> 1, half = xcd & 1;
    int wave = threadIdx.x >> 6, lane = threadIdx.x & 63;
    int fp = lane & 15;          // feature-pair within 32-feat plane
    int g = lane >> 4;           // node group 0..3
    int slot = half * Nh + (b >> 3) * 16 + wave * 4 + g;
    int lim = min(n, (half + 1) * Nh);
    bool act = slot < lim;
    int node = perm[act ? slot : (lim - 1)];

    const unsigned short* gp = gs + (size_t)plane * ((size_t)n * 16);
    int beg = cursor[node];
    int ne = act ? cnt[node] : 0;

    float sx, sy;
    gather_plane(csr_src, gp, beg, beg + ne, node, fp, sx, sy);

    float dv = dinv[node];
    float2 bv = ((const float2*)bias)[plane * 16 + fp];
    float2 r;
    r.x = fmaxf(sx * dv + bv.x, 0.0f);
    r.y = fmaxf(sy * dv + bv.y, 0.0f);
    union { __hip_bfloat162 h; unsigned int u; } cv;
    cv.h = __float22bfloat162_rn(r);
    if (act)
        __builtin_nontemporal_store(cv.u, &outb[(size_t)node * 64 + plane * 16 + fp]);
}

// ---- mean pool stage 1 (bf16 input, 1024 blocks) ----
__global__ __launch_bounds__(256) void pool_kernel(const __hip_bfloat16* __restrict__ a,
                                                   float* __restrict__ pooled, int n) {
    int tid = blockIdx.x * 256 + threadIdx.x;  // 1024 blocks -> 262144 threads
    int f = tid & 127;
    int i0 = tid >> 7;  // 0..2047
    float s = 0.0f;
    for (int i = i0; i < n; i += 2048) s += __bfloat162float(a[(size_t)i * FEAT + f]);
    atomicAdd(&pooled[f], s);
}

// ---- final: out[c] = (pooled/N) . Wc[:,c] + bc[c] ----
__global__ __launch_bounds__(128) void final_kernel(const float* __restrict__ pooled,
                                                    const float* __restrict__ Wc,
                                                    const float* __restrict__ bc,
                                                    float* __restrict__ out,
                                                    int n, int C) {
    __shared__ float p[FEAT];
    int t = threadIdx.x;
    p[t] = pooled[t] * (1.0f / (float)n);
    __syncthreads();
    if (t < C) {
        float acc = bc[t];
        for (int h = 0; h < FEAT; h++)
            acc += p[h] * Wc[h * C + t];
        out[t] = acc;
    }
}

extern "C" void kernel_launch(void* const* d_in, const int* in_sizes, int n_in,
                              void* d_out, int out_size, void* d_ws, size_t ws_size,
                              hipStream_t stream) {
    const float* x  = (const float*)d_in[0];
    const int*   ei = (const int*)d_in[1];
    const float* W1 = (const float*)d_in[2];
    const float* b1 = (const float*)d_in[3];
    const float* W2 = (const float*)d_in[4];
    const float* b2 = (const float*)d_in[5];
    const float* Wc = (const float*)d_in[6];
    const float* bc = (const float*)d_in[7];

    const int N = in_sizes[0] / FEAT;        // 100000
    const int E = in_sizes[1] / 2;           // 1600000
    const int C = out_size;                  // 32
    const int* srcI = ei;
    const int* dstI = ei + E;
    const int NC = (E + CHUNK - 1) / CHUNK;  // edge chunks (391, <= 512)
    const int NBK = (N + 255) >> 8;          // node buckets (391, <= MAXBUCK)

    // workspace carve (256B aligned)
    auto align256 = [](size_t v) { return (v + 255) & ~(size_t)255; };
    char* w = (char*)d_ws;
    int*            cnt     = (int*)w;            w += align256((size_t)N * 4);
    float*          dinv    = (float*)w;          w += align256((size_t)N * 4);
    int*            cursor  = (int*)w;            w += align256((size_t)N * 4);
    int*            perm    = (int*)w;            w += align256((size_t)N * 4);
    int*            csr_src = (int*)w;            w += align256((size_t)E * 4);
    int*            binned  = (int*)w;            w += align256((size_t)E * 4);
    int*            hist    = (int*)w;            w += align256((size_t)NBK * NC * 4);
    int*            hoff    = (int*)w;            w += align256((size_t)NBK * NC * 4);
    int*            btot    = (int*)w;            w += align256((size_t)NBK * 4);
    int*            bboff   = (int*)w;            w += align256((size_t)(NBK + 1) * 4);
    unsigned short* Wbf1    = (unsigned short*)w; w += align256((size_t)FEAT * FEAT * 2);
    unsigned short* Wbf2    = (unsigned short*)w; w += align256((size_t)FEAT * FEAT * 2);
    unsigned char*  gbuf    = (unsigned char*)w;  w += align256((size_t)N * FEAT);
    unsigned short* bufA    = (unsigned short*)w; w += align256((size_t)N * FEAT * 2);
    float*          pooled  = (float*)w;          w += align256((size_t)FEAT * 4);

    // W pre-pack (both layers) + pooled zero
    wprep2<<<128, 256, 0, stream>>>(W1, W2, Wbf1, Wbf2, pooled);

    // ---- atomic-free CSR build (all kernels >= 391 blocks except bscan) ----
    hist2<<<NC, 256, 0, stream>>>(dstI, hist, E, NC, NBK);
    rowsum_k<<<NBK, 256, 0, stream>>>(hist, btot, NC);
    bscan_k<<<1, 512, 0, stream>>>(btot, bboff, NBK);
    rowoff_k<<<NBK, 512, 0, stream>>>(hist, bboff, hoff, NC);
    fill2<<<NC, 256, 0, stream>>>(srcI, dstI, hoff, binned, E, NC, NBK);
    bucket_scat<<<NBK, 256, 0, stream>>>(binned, bboff, cnt, dinv, cursor, csr_src,
                                         perm, N);

    const int gGemm = (N + 63) / 64;
    const int Nh = (N + 1) >> 1;             // slots per half
    const int gAgg = ((Nh + 15) / 16) * 8;   // 8 XCD-pinned lanes of blocks

    // ---- layer 1 ----
    gemm_mfma<true><<<gGemm, 256, 0, stream>>>(x, Wbf1, dinv, gbuf, N);
    agg_planes<<<gAgg, 256, 0, stream>>>(cursor, cnt, csr_src,
                                         (const unsigned short*)gbuf, dinv, b1, perm,
                                         (unsigned int*)bufA, N, Nh);

    // ---- layer 2 ----
    gemm_mfma<false><<<gGemm, 256, 0, stream>>>(bufA, Wbf2, dinv, gbuf, N);
    agg_planes<<<gAgg, 256, 0, stream>>>(cursor, cnt, csr_src,
                                         (const unsigned short*)gbuf, dinv, b2, perm,
                                         (unsigned int*)bufA, N, Nh);

    // ---- pool + classifier ----
    pool_kernel<<<1024, 256, 0, stream>>>((const __hip_bfloat16*)bufA, pooled, N);
    final_kernel<<<1, 128, 0, stream>>>(pooled, Wc, bc, (float*)d_out, N, C);
}

// Round 4
// 370.533 us; speedup vs baseline: 1.6071x; 1.2228x over previous
//
#include <hip/hip_runtime.h>
#include <hip/hip_bf16.h>

// GCN: h1 = relu(Agg(x@W1)+b1); h2 = relu(Agg(h1@W2)+b2); out = mean(h2)@Wc + bc
// Agg via CSR gather; g = (X@W)*dinv stored OCP fp8 e4m3 (128B node-major rows).
// agg_csr is at its structural floor for this layout: FETCH = 8 XCDs x 12.8MB
// gbuf (LLC->L2 duplication), ~1.8 TB/s effective. 1 node/wave + 100k-wave
// oversubscription required (r10 A/B: 16-serial-node fusion halved throughput).
// r1-r3 lessons (plane-sharded L2-resident gather): FETCH drops 89.6->37MB but
// 32B plane rows double L2 transactions per byte and lengthen the dependent
// chain -> 102-173us, strictly worse than 64us. Node-major 128B rows win.
// NEW r4: activations h1/h2 stored fp8 e4m3 (not bf16): halves agg WRITE
// (25->12.5MB), GEMM2 A-read and pool read. fp8->bf16 decode is exact.
// CSR build atomic-free; ALL build kernels >= 391 blocks (r11: narrow build
// kernels were width-starved, ~270us invisible tail).
// GEMMs: mfma_f32_16x16x32_bf16, LDS-free, W pre-packed to k-block layout.

#define FEAT 128
#define CHUNK 4096      // edges per chunk (391 chunks)
#define MAXBUCK 512     // max node-buckets (N <= 131072); also NC cap
#define ECAP 12288      // LDS edge staging cap in bucket_scat (48 KB of int)

typedef __attribute__((ext_vector_type(8))) short short8;
typedef __attribute__((ext_vector_type(4))) float float4v;
typedef __attribute__((ext_vector_type(2))) float floatx2;

union I4S8 { int4 i; short8 s; };

static __device__ inline unsigned short f2bf(float f) {
    union { __hip_bfloat16 h; unsigned short u; } cv;
    cv.h = __float2bfloat16(f);
    return cv.u;
}

// ---- OCP fp8 e4m3 helpers ----
static __device__ inline floatx2 fp8x2_dec(unsigned int u) {
#if __has_builtin(__builtin_amdgcn_cvt_pk_f32_fp8)
    return __builtin_amdgcn_cvt_pk_f32_fp8((int)u, false);
#else
    floatx2 r;
    unsigned int b0 = u & 0xFFu, b1 = (u >> 8) & 0xFFu;
    r.x = __uint_as_float(((b0 & 0x80u) << 24) | ((b0 & 0x7Fu) << 20)) * 0x1p+120f;
    r.y = __uint_as_float(((b1 & 0x80u) << 24) | ((b1 & 0x7Fu) << 20)) * 0x1p+120f;
    return r;
#endif
}

static __device__ inline floatx2 fp8x2_dec_hi(unsigned int u) {
#if __has_builtin(__builtin_amdgcn_cvt_pk_f32_fp8)
    return __builtin_amdgcn_cvt_pk_f32_fp8((int)u, true);
#else
    return fp8x2_dec(u >> 16);
#endif
}

// pack two floats -> two fp8 e4m3 bytes (low word)
static __device__ inline unsigned short fp8x2_enc(float x, float y) {
#if __has_builtin(__builtin_amdgcn_cvt_pk_fp8_f32)
    return (unsigned short)(__builtin_amdgcn_cvt_pk_fp8_f32(x, y, 0, false) & 0xFFFF);
#else
    // scalar fallback
    auto enc1 = [](float f) -> unsigned int {
        unsigned int u = __float_as_uint(f);
        unsigned int s = (u >> 24) & 0x80u;
        float a = fabsf(f);
        a = fminf(a, 448.0f);
        unsigned int code;
        if (a < 0.015625f) {
            code = (unsigned int)(int)rintf(a * 512.0f);
        } else {
            unsigned int au = __float_as_uint(a);
            unsigned int r = au + 0x0007FFFFu + ((au >> 20) & 1u);
            unsigned int e = (r >> 23) - 120u;
            unsigned int m = (r >> 20) & 7u;
            code = (e << 3) | m;
            if (code > 0x7Eu) code = 0x7Eu;
        }
        return code | s;
    };
    return (unsigned short)(enc1(x) | (enc1(y) << 8));
#endif
}

static __device__ inline unsigned char fp8enc(float f) {
#if __has_builtin(__builtin_amdgcn_cvt_pk_fp8_f32)
    return (unsigned char)(__builtin_amdgcn_cvt_pk_fp8_f32(f, 0.0f, 0, false) & 0xFF);
#else
    return (unsigned char)(fp8x2_enc(f, 0.0f) & 0xFF);
#endif
}

// ---- build phase 1: per-chunk histogram over node buckets (dst>>8) ----
__global__ __launch_bounds__(256) void hist2(const int* __restrict__ dst,
                                             int* __restrict__ hist,
                                             int nE, int NC, int nbuck) {
    __shared__ int h[MAXBUCK];
    int c = blockIdx.x, t = threadIdx.x;
    for (int i = t; i < nbuck; i += 256) h[i] = 0;
    __syncthreads();
    int beg = c * CHUNK, end = min(nE, beg + CHUNK);
    for (int e = beg + t; e < end; e += 256)
        atomicAdd(&h[dst[e] >> 8], 1);
    __syncthreads();
    for (int i = t; i < nbuck; i += 256) hist[i * NC + c] = h[i];
}

// ---- phase 2a: per-bucket totals (wide: one block per bucket) ----
__global__ __launch_bounds__(256) void rowsum_k(const int* __restrict__ hist,
                                                int* __restrict__ btot, int NC) {
    __shared__ int red[256];
    int b = blockIdx.x, t = threadIdx.x;
    int s = 0;
    for (int c = t; c < NC; c += 256) s += hist[b * NC + c];
    red[t] = s;
    __syncthreads();
    for (int o = 128; o > 0; o >>= 1) {
        if (t < o) red[t] += red[t + o];
        __syncthreads();
    }
    if (t == 0) btot[b] = red[0];
}

// ---- phase 2b: exclusive scan of bucket totals (nbuck <= 512) ----
__global__ __launch_bounds__(512) void bscan_k(const int* __restrict__ btot,
                                               int* __restrict__ bboff, int nbuck) {
    __shared__ int sc[512];
    int t = threadIdx.x;
    int v = (t < nbuck) ? btot[t] : 0;
    sc[t] = v;
    __syncthreads();
    for (int o = 1; o < 512; o <<= 1) {
        int add = (t >= o) ? sc[t - o] : 0;
        __syncthreads();
        sc[t] += add;
        __syncthreads();
    }
    if (t < nbuck) {
        bboff[t] = sc[t] - v;
        if (t == nbuck - 1) bboff[nbuck] = sc[t];
    }
}

// ---- phase 2c: per-(bucket,chunk) offsets (wide: block-parallel scan, NC<=512) ----
__global__ __launch_bounds__(512) void rowoff_k(const int* __restrict__ hist,
                                                const int* __restrict__ bboff,
                                                int* __restrict__ hoff, int NC) {
    __shared__ int sc[512];
    int b = blockIdx.x, t = threadIdx.x;
    int v = (t < NC) ? hist[b * NC + t] : 0;
    sc[t] = v;
    __syncthreads();
    for (int o = 1; o < 512; o <<= 1) {
        int add = (t >= o) ? sc[t - o] : 0;
        __syncthreads();
        sc[t] += add;
        __syncthreads();
    }
    if (t < NC) hoff[b * NC + t] = bboff[b] + sc[t] - v;
}

// ---- phase 3: pack (src<<8|dloc) bucket-grouped; LDS cursors ----
__global__ __launch_bounds__(256) void fill2(const int* __restrict__ src,
                                             const int* __restrict__ dst,
                                             const int* __restrict__ off,
                                             int* __restrict__ binned,
                                             int nE, int NC, int nbuck) {
    __shared__ int cur[MAXBUCK];
    int c = blockIdx.x, t = threadIdx.x;
    for (int i = t; i < nbuck; i += 256) cur[i] = off[i * NC + c];
    __syncthreads();
    int beg = c * CHUNK, end = min(nE, beg + CHUNK);
    for (int e = beg + t; e < end; e += 256) {
        int d = dst[e];
        int pos = atomicAdd(&cur[d >> 8], 1);
        binned[pos] = (src[e] << 8) | (d & 255);
    }
}

// ---- phase 4: per-bucket count + dinv + cursor + csr scatter (all LDS) ----
__global__ __launch_bounds__(256) void bucket_scat(const int* __restrict__ binned,
                                                   const int* __restrict__ bboff,
                                                   int* __restrict__ cnt,
                                                   float* __restrict__ dinv,
                                                   int* __restrict__ cursor,
                                                   int* __restrict__ csr_src, int n) {
    __shared__ int se[ECAP];
    __shared__ int lcnt[256];
    __shared__ int lcur[256];
    __shared__ int ssc[256];
    int b = blockIdx.x, t = threadIdx.x;
    int node0 = b << 8;
    int nloc = min(256, n - node0);
    int ebeg = bboff[b], eend = bboff[b + 1];
    int ne = eend - ebeg;
    lcnt[t] = 0;
    __syncthreads();
    bool staged = (ne <= ECAP);
    if (staged) {
        for (int i = t; i < ne; i += 256) {
            int e = binned[ebeg + i];
            se[i] = e;
            atomicAdd(&lcnt[e & 255], 1);
        }
    } else {
        for (int i = t; i < ne; i += 256)
            atomicAdd(&lcnt[binned[ebeg + i] & 255], 1);
    }
    __syncthreads();
    int myc = (t < nloc) ? lcnt[t] : 0;
    ssc[t] = myc;
    __syncthreads();
    for (int o = 1; o < 256; o <<= 1) {
        int add = (t >= o) ? ssc[t - o] : 0;
        __syncthreads();
        ssc[t] += add;
        __syncthreads();
    }
    int excl = ssc[t] - myc;
    if (t < nloc) {
        cnt[node0 + t] = myc;
        dinv[node0 + t] = rsqrtf((float)(myc + 1));
        cursor[node0 + t] = ebeg + excl;   // cursor = start of node's list
        lcur[t] = excl;
    }
    __syncthreads();
    if (staged) {
        for (int i = t; i < ne; i += 256) {
            int e = se[i];
            int pos = atomicAdd(&lcur[e & 255], 1);
            csr_src[ebeg + pos] = ((unsigned int)e) >> 8;
        }
    } else {
        for (int i = t; i < ne; i += 256) {
            int e = binned[ebeg + i];
            int pos = atomicAdd(&lcur[e & 255], 1);
            csr_src[ebeg + pos] = ((unsigned int)e) >> 8;
        }
    }
}

// ---- W pre-pack (both layers) + pooled zero-init ----
__global__ __launch_bounds__(256) void wprep2(const float* __restrict__ W1,
                                              const float* __restrict__ W2,
                                              unsigned short* __restrict__ Wbf1,
                                              unsigned short* __restrict__ Wbf2,
                                              float* __restrict__ pooled) {
    int tid = blockIdx.x * 256 + threadIdx.x;   // 32768 threads
    if (tid < FEAT) pooled[tid] = 0.0f;
    const float* W = (tid < 16384) ? W1 : W2;
    unsigned short* O = (tid < 16384) ? Wbf1 : Wbf2;
    int id = tid & 16383;
    int chunk = id >> 3, j = id & 7;
    int kb = chunk >> 7, nn = chunk & 127;
    O[id] = f2bf(W[(kb * 8 + j) * FEAT + nn]);
}

// ---- MFMA GEMM: gout[N][128](fp8) = bf16(X) @ Wbf * dinv[row] ----
// AFP32=true: X is fp32 rows. AFP32=false: X is fp8 e4m3 rows (exact->bf16).
template <bool AFP32>
__global__ __launch_bounds__(256) void gemm_mfma(const void* __restrict__ Xv,
                                                 const unsigned short* __restrict__ Wbf,
                                                 const float* __restrict__ dinv,
                                                 unsigned char* __restrict__ gout,
                                                 int n) {
    int wave = threadIdx.x >> 6, lane = threadIdx.x & 63;
    int m0 = blockIdx.x * 64 + wave * 16;
    if (m0 >= n) return;
    int col = lane & 15, quad = lane >> 4;
    int mc = min(m0 + col, n - 1);

    short8 afr[4];
    if (AFP32) {
        const float* X = (const float*)Xv;
        const float* xr = X + (size_t)mc * FEAT + quad * 8;
#pragma unroll
        for (int ks = 0; ks < 4; ks++) {
            float4 lo = *(const float4*)(xr + ks * 32);
            float4 hi = *(const float4*)(xr + ks * 32 + 4);
            short8 a;
            a[0] = (short)f2bf(lo.x); a[1] = (short)f2bf(lo.y);
            a[2] = (short)f2bf(lo.z); a[3] = (short)f2bf(lo.w);
            a[4] = (short)f2bf(hi.x); a[5] = (short)f2bf(hi.y);
            a[6] = (short)f2bf(hi.z); a[7] = (short)f2bf(hi.w);
            afr[ks] = a;
        }
    } else {
        const unsigned char* X8 = (const unsigned char*)Xv;
        const unsigned char* xr = X8 + (size_t)mc * FEAT + quad * 8;
#pragma unroll
        for (int ks = 0; ks < 4; ks++) {
            uint2 u2 = *(const uint2*)(xr + ks * 32);
            floatx2 p0 = fp8x2_dec(u2.x);
            floatx2 p1 = fp8x2_dec_hi(u2.x);
            floatx2 p2 = fp8x2_dec(u2.y);
            floatx2 p3 = fp8x2_dec_hi(u2.y);
            short8 a;
            a[0] = (short)f2bf(p0.x); a[1] = (short)f2bf(p0.y);
            a[2] = (short)f2bf(p1.x); a[3] = (short)f2bf(p1.y);
            a[4] = (short)f2bf(p2.x); a[5] = (short)f2bf(p2.y);
            a[6] = (short)f2bf(p3.x); a[7] = (short)f2bf(p3.y);
            afr[ks] = a;
        }
    }

    float dvr[4];
#pragma unroll
    for (int r = 0; r < 4; r++)
        dvr[r] = dinv[min(m0 + quad * 4 + r, n - 1)];

    const int4* Wb = (const int4*)Wbf;
#pragma unroll
    for (int nt = 0; nt < 8; nt++) {
        float4v acc = {0.f, 0.f, 0.f, 0.f};
#pragma unroll
        for (int ks = 0; ks < 4; ks++) {
            int kb = ks * 4 + quad;
            I4S8 u; u.i = Wb[kb * FEAT + nt * 16 + col];
            acc = __builtin_amdgcn_mfma_f32_16x16x32_bf16(afr[ks], u.s, acc, 0, 0, 0);
        }
#pragma unroll
        for (int r = 0; r < 4; r++) {
            int row = m0 + quad * 4 + r;
            if (row < n)
                gout[(size_t)row * FEAT + nt * 16 + col] = fp8enc(acc[r] * dvr[r]);
        }
    }
}

// ---- gather-sum core for one node (fp8 rows, 2 feats/lane) ----
static __device__ inline void gather_node(const int* __restrict__ csr_src,
                                          const unsigned short* __restrict__ gs,
                                          int beg, int end, int node, int lane,
                                          float& sx, float& sy) {
    floatx2 sl = fp8x2_dec(gs[(size_t)node * 64 + lane]);   // self-loop term
    float ax[4] = {sl.x, 0.f, 0.f, 0.f};
    float ay[4] = {sl.y, 0.f, 0.f, 0.f};
    int j = beg;
    for (; j + 15 < end; j += 16) {
        int sIdx[16];
#pragma unroll
        for (int k = 0; k < 16; k++) sIdx[k] = csr_src[j + k];
        unsigned int uu[16];
#pragma unroll
        for (int k = 0; k < 16; k++) uu[k] = gs[(size_t)sIdx[k] * 64 + lane];
#pragma unroll
        for (int k = 0; k < 16; k++) {
            floatx2 v = fp8x2_dec(uu[k]);
            ax[k & 3] += v.x;
            ay[k & 3] += v.y;
        }
    }
    for (; j + 3 < end; j += 4) {
        int sIdx[4];
#pragma unroll
        for (int k = 0; k < 4; k++) sIdx[k] = csr_src[j + k];
        unsigned int uu[4];
#pragma unroll
        for (int k = 0; k < 4; k++) uu[k] = gs[(size_t)sIdx[k] * 64 + lane];
#pragma unroll
        for (int k = 0; k < 4; k++) {
            floatx2 v = fp8x2_dec(uu[k]);
            ax[k] += v.x;
            ay[k] += v.y;
        }
    }
    for (; j < end; j++) {
        floatx2 v = fp8x2_dec(gs[(size_t)csr_src[j] * 64 + lane]);
        ax[0] += v.x;
        ay[0] += v.y;
    }
    sx = (ax[0] + ax[1]) + (ax[2] + ax[3]);
    sy = (ay[0] + ay[1]) + (ay[2] + ay[3]);
}

// ---- agg: CSR gather + bias + relu -> fp8 rows (1 node per wave) ----
__global__ __launch_bounds__(256) void agg_csr(const int* __restrict__ cursor,
                                               const int* __restrict__ cnt,
                                               const int* __restrict__ csr_src,
                                               const unsigned short* __restrict__ gs,
                                               const float* __restrict__ dinv,
                                               const float* __restrict__ bias,
                                               unsigned short* __restrict__ outb,
                                               int n) {
    int node = blockIdx.x * 4 + (threadIdx.x >> 6);
    if (node >= n) return;
    int lane = threadIdx.x & 63;
    int beg = cursor[node];
    int end = beg + cnt[node];
    float sx, sy;
    gather_node(csr_src, gs, beg, end, node, lane, sx, sy);
    float dv = dinv[node];
    float2 bv = ((const float2*)bias)[lane];
    float rx = fmaxf(sx * dv + bv.x, 0.0f);
    float ry = fmaxf(sy * dv + bv.y, 0.0f);
    outb[(size_t)node * 64 + lane] = fp8x2_enc(rx, ry);
}

// ---- mean pool stage 1 (fp8 input, 1024 blocks) ----
__global__ __launch_bounds__(256) void pool_kernel(const unsigned char* __restrict__ a,
                                                   float* __restrict__ pooled, int n) {
    int tid = blockIdx.x * 256 + threadIdx.x;  // 1024 blocks -> 262144 threads
    int f = tid & 127;
    int i0 = tid >> 7;  // 0..2047
    float s = 0.0f;
    for (int i = i0; i < n; i += 2048)
        s += fp8x2_dec((unsigned int)a[(size_t)i * FEAT + f]).x;
    atomicAdd(&pooled[f], s);
}

// ---- final: out[c] = (pooled/N) . Wc[:,c] + bc[c] ----
__global__ __launch_bounds__(128) void final_kernel(const float* __restrict__ pooled,
                                                    const float* __restrict__ Wc,
                                                    const float* __restrict__ bc,
                                                    float* __restrict__ out,
                                                    int n, int C) {
    __shared__ float p[FEAT];
    int t = threadIdx.x;
    p[t] = pooled[t] * (1.0f / (float)n);
    __syncthreads();
    if (t < C) {
        float acc = bc[t];
        for (int h = 0; h < FEAT; h++)
            acc += p[h] * Wc[h * C + t];
        out[t] = acc;
    }
}

extern "C" void kernel_launch(void* const* d_in, const int* in_sizes, int n_in,
                              void* d_out, int out_size, void* d_ws, size_t ws_size,
                              hipStream_t stream) {
    const float* x  = (const float*)d_in[0];
    const int*   ei = (const int*)d_in[1];
    const float* W1 = (const float*)d_in[2];
    const float* b1 = (const float*)d_in[3];
    const float* W2 = (const float*)d_in[4];
    const float* b2 = (const float*)d_in[5];
    const float* Wc = (const float*)d_in[6];
    const float* bc = (const float*)d_in[7];

    const int N = in_sizes[0] / FEAT;        // 100000
    const int E = in_sizes[1] / 2;           // 1600000
    const int C = out_size;                  // 32
    const int* srcI = ei;
    const int* dstI = ei + E;
    const int NC = (E + CHUNK - 1) / CHUNK;  // edge chunks (391, <= 512)
    const int NBK = (N + 255) >> 8;          // node buckets (391, <= MAXBUCK)

    // workspace carve (256B aligned)
    auto align256 = [](size_t v) { return (v + 255) & ~(size_t)255; };
    char* w = (char*)d_ws;
    int*            cnt     = (int*)w;            w += align256((size_t)N * 4);
    float*          dinv    = (float*)w;          w += align256((size_t)N * 4);
    int*            cursor  = (int*)w;            w += align256((size_t)N * 4);
    int*            csr_src = (int*)w;            w += align256((size_t)E * 4);
    int*            binned  = (int*)w;            w += align256((size_t)E * 4);
    int*            hist    = (int*)w;            w += align256((size_t)NBK * NC * 4);
    int*            hoff    = (int*)w;            w += align256((size_t)NBK * NC * 4);
    int*            btot    = (int*)w;            w += align256((size_t)NBK * 4);
    int*            bboff   = (int*)w;            w += align256((size_t)(NBK + 1) * 4);
    unsigned short* Wbf1    = (unsigned short*)w; w += align256((size_t)FEAT * FEAT * 2);
    unsigned short* Wbf2    = (unsigned short*)w; w += align256((size_t)FEAT * FEAT * 2);
    unsigned char*  gbuf    = (unsigned char*)w;  w += align256((size_t)N * FEAT);
    unsigned char*  bufA    = (unsigned char*)w;  w += align256((size_t)N * FEAT);
    float*          pooled  = (float*)w;          w += align256((size_t)FEAT * 4);

    // W pre-pack (both layers) + pooled zero
    wprep2<<<128, 256, 0, stream>>>(W1, W2, Wbf1, Wbf2, pooled);

    // ---- atomic-free CSR build (all kernels >= 391 blocks except bscan) ----
    hist2<<<NC, 256, 0, stream>>>(dstI, hist, E, NC, NBK);
    rowsum_k<<<NBK, 256, 0, stream>>>(hist, btot, NC);
    bscan_k<<<1, 512, 0, stream>>>(btot, bboff, NBK);
    rowoff_k<<<NBK, 512, 0, stream>>>(hist, bboff, hoff, NC);
    fill2<<<NC, 256, 0, stream>>>(srcI, dstI, hoff, binned, E, NC, NBK);
    bucket_scat<<<NBK, 256, 0, stream>>>(binned, bboff, cnt, dinv, cursor, csr_src, N);

    const int gGemm = (N + 63) / 64;
    const int gAgg = (N + 3) / 4;

    // ---- layer 1 ----
    gemm_mfma<true><<<gGemm, 256, 0, stream>>>(x, Wbf1, dinv, gbuf, N);
    agg_csr<<<gAgg, 256, 0, stream>>>(cursor, cnt, csr_src,
                                      (const unsigned short*)gbuf, dinv, b1,
                                      (unsigned short*)bufA, N);

    // ---- layer 2 ----
    gemm_mfma<false><<<gGemm, 256, 0, stream>>>(bufA, Wbf2, dinv, gbuf, N);
    agg_csr<<<gAgg, 256, 0, stream>>>(cursor, cnt, csr_src,
                                      (const unsigned short*)gbuf, dinv, b2,
                                      (unsigned short*)bufA, N);

    // ---- pool + classifier ----
    pool_kernel<<<1024, 256, 0, stream>>>(bufA, pooled, N);
    final_kernel<<<1, 128, 0, stream>>>(pooled, Wc, bc, (float*)d_out, N, C);
}

// Round 5
// 354.660 us; speedup vs baseline: 1.6790x; 1.0448x over previous
//
#include <hip/hip_runtime.h>
#include <hip/hip_bf16.h>

// GCN: h1 = relu(Agg(x@W1)+b1); h2 = relu(Agg(h1@W2)+b2); out = mean(h2)@Wc + bc
// Agg via CSR gather; g = (X@W)*dinv stored OCP fp8 e4m3 (128B node-major rows).
// r4 analysis: agg_csr = VALU(address-arith) + latency interleave. 45% VALUBusy
// = ~22 VALU/edge, ~18 of them 64-bit address chains. r5: 32-bit unsigned
// byte offsets against wave-uniform SGPR bases (saddr form): offB =
// (src<<7)|(lane<<1) -> 1 VALU/gather, idx = jb+4k literal-add -> 1 VALU.
// fp8 decode via v_cvt_pk_f32_fp8, packed v_pk_add_f32 accumulate.
// r1-r3 lessons (plane-sharded L2-resident gather): FETCH drops 89.6->37MB but
// 32B plane rows double L2 transactions per byte and lengthen the dependent
// chain -> 102-173us, strictly worse than 64us. Node-major 128B rows win.
// r4: activations h1/h2 fp8 e4m3 (halves agg WRITE; write-invisible -> agg is
// fetch/latency+VALU bound, confirmed).
// CSR build atomic-free; ALL build kernels >= 391 blocks (r11: narrow build
// kernels were width-starved, ~270us invisible tail).
// GEMMs: mfma_f32_16x16x32_bf16, LDS-free, W pre-packed to k-block layout.

#define FEAT 128
#define CHUNK 4096      // edges per chunk (391 chunks)
#define MAXBUCK 512     // max node-buckets (N <= 131072); also NC cap
#define ECAP 12288      // LDS edge staging cap in bucket_scat (48 KB of int)

typedef __attribute__((ext_vector_type(8))) short short8;
typedef __attribute__((ext_vector_type(4))) float float4v;
typedef __attribute__((ext_vector_type(2))) float floatx2;

union I4S8 { int4 i; short8 s; };

static __device__ inline unsigned short f2bf(float f) {
    union { __hip_bfloat16 h; unsigned short u; } cv;
    cv.h = __float2bfloat16(f);
    return cv.u;
}

// ---- OCP fp8 e4m3 helpers ----
static __device__ inline floatx2 fp8x2_dec(unsigned int u) {
#if __has_builtin(__builtin_amdgcn_cvt_pk_f32_fp8)
    return __builtin_amdgcn_cvt_pk_f32_fp8((int)u, false);
#else
    floatx2 r;
    unsigned int b0 = u & 0xFFu, b1 = (u >> 8) & 0xFFu;
    r.x = __uint_as_float(((b0 & 0x80u) << 24) | ((b0 & 0x7Fu) << 20)) * 0x1p+120f;
    r.y = __uint_as_float(((b1 & 0x80u) << 24) | ((b1 & 0x7Fu) << 20)) * 0x1p+120f;
    return r;
#endif
}

static __device__ inline floatx2 fp8x2_dec_hi(unsigned int u) {
#if __has_builtin(__builtin_amdgcn_cvt_pk_f32_fp8)
    return __builtin_amdgcn_cvt_pk_f32_fp8((int)u, true);
#else
    return fp8x2_dec(u >> 16);
#endif
}

// pack two floats -> two fp8 e4m3 bytes (low word)
static __device__ inline unsigned short fp8x2_enc(float x, float y) {
#if __has_builtin(__builtin_amdgcn_cvt_pk_fp8_f32)
    return (unsigned short)(__builtin_amdgcn_cvt_pk_fp8_f32(x, y, 0, false) & 0xFFFF);
#else
    auto enc1 = [](float f) -> unsigned int {
        unsigned int u = __float_as_uint(f);
        unsigned int s = (u >> 24) & 0x80u;
        float a = fabsf(f);
        a = fminf(a, 448.0f);
        unsigned int code;
        if (a < 0.015625f) {
            code = (unsigned int)(int)rintf(a * 512.0f);
        } else {
            unsigned int au = __float_as_uint(a);
            unsigned int r = au + 0x0007FFFFu + ((au >> 20) & 1u);
            unsigned int e = (r >> 23) - 120u;
            unsigned int m = (r >> 20) & 7u;
            code = (e << 3) | m;
            if (code > 0x7Eu) code = 0x7Eu;
        }
        return code | s;
    };
    return (unsigned short)(enc1(x) | (enc1(y) << 8));
#endif
}

static __device__ inline unsigned char fp8enc(float f) {
#if __has_builtin(__builtin_amdgcn_cvt_pk_fp8_f32)
    return (unsigned char)(__builtin_amdgcn_cvt_pk_fp8_f32(f, 0.0f, 0, false) & 0xFF);
#else
    return (unsigned char)(fp8x2_enc(f, 0.0f) & 0xFF);
#endif
}

// ---- build phase 1: per-chunk histogram over node buckets (dst>>8) ----
__global__ __launch_bounds__(256) void hist2(const int* __restrict__ dst,
                                             int* __restrict__ hist,
                                             int nE, int NC, int nbuck) {
    __shared__ int h[MAXBUCK];
    int c = blockIdx.x, t = threadIdx.x;
    for (int i = t; i < nbuck; i += 256) h[i] = 0;
    __syncthreads();
    int beg = c * CHUNK, end = min(nE, beg + CHUNK);
    for (int e = beg + t; e < end; e += 256)
        atomicAdd(&h[dst[e] >> 8], 1);
    __syncthreads();
    for (int i = t; i < nbuck; i += 256) hist[i * NC + c] = h[i];
}

// ---- phase 2a: per-bucket totals (wide: one block per bucket) ----
__global__ __launch_bounds__(256) void rowsum_k(const int* __restrict__ hist,
                                                int* __restrict__ btot, int NC) {
    __shared__ int red[256];
    int b = blockIdx.x, t = threadIdx.x;
    int s = 0;
    for (int c = t; c < NC; c += 256) s += hist[b * NC + c];
    red[t] = s;
    __syncthreads();
    for (int o = 128; o > 0; o >>= 1) {
        if (t < o) red[t] += red[t + o];
        __syncthreads();
    }
    if (t == 0) btot[b] = red[0];
}

// ---- phase 2b: exclusive scan of bucket totals (nbuck <= 512) ----
__global__ __launch_bounds__(512) void bscan_k(const int* __restrict__ btot,
                                               int* __restrict__ bboff, int nbuck) {
    __shared__ int sc[512];
    int t = threadIdx.x;
    int v = (t < nbuck) ? btot[t] : 0;
    sc[t] = v;
    __syncthreads();
    for (int o = 1; o < 512; o <<= 1) {
        int add = (t >= o) ? sc[t - o] : 0;
        __syncthreads();
        sc[t] += add;
        __syncthreads();
    }
    if (t < nbuck) {
        bboff[t] = sc[t] - v;
        if (t == nbuck - 1) bboff[nbuck] = sc[t];
    }
}

// ---- phase 2c: per-(bucket,chunk) offsets (wide: block-parallel scan, NC<=512) ----
__global__ __launch_bounds__(512) void rowoff_k(const int* __restrict__ hist,
                                                const int* __restrict__ bboff,
                                                int* __restrict__ hoff, int NC) {
    __shared__ int sc[512];
    int b = blockIdx.x, t = threadIdx.x;
    int v = (t < NC) ? hist[b * NC + t] : 0;
    sc[t] = v;
    __syncthreads();
    for (int o = 1; o < 512; o <<= 1) {
        int add = (t >= o) ? sc[t - o] : 0;
        __syncthreads();
        sc[t] += add;
        __syncthreads();
    }
    if (t < NC) hoff[b * NC + t] = bboff[b] + sc[t] - v;
}

// ---- phase 3: pack (src<<8|dloc) bucket-grouped; LDS cursors ----
__global__ __launch_bounds__(256) void fill2(const int* __restrict__ src,
                                             const int* __restrict__ dst,
                                             const int* __restrict__ off,
                                             int* __restrict__ binned,
                                             int nE, int NC, int nbuck) {
    __shared__ int cur[MAXBUCK];
    int c = blockIdx.x, t = threadIdx.x;
    for (int i = t; i < nbuck; i += 256) cur[i] = off[i * NC + c];
    __syncthreads();
    int beg = c * CHUNK, end = min(nE, beg + CHUNK);
    for (int e = beg + t; e < end; e += 256) {
        int d = dst[e];
        int pos = atomicAdd(&cur[d >> 8], 1);
        binned[pos] = (src[e] << 8) | (d & 255);
    }
}

// ---- phase 4: per-bucket count + dinv + cursor + csr scatter (all LDS) ----
__global__ __launch_bounds__(256) void bucket_scat(const int* __restrict__ binned,
                                                   const int* __restrict__ bboff,
                                                   int* __restrict__ cnt,
                                                   float* __restrict__ dinv,
                                                   int* __restrict__ cursor,
                                                   int* __restrict__ csr_src, int n) {
    __shared__ int se[ECAP];
    __shared__ int lcnt[256];
    __shared__ int lcur[256];
    __shared__ int ssc[256];
    int b = blockIdx.x, t = threadIdx.x;
    int node0 = b << 8;
    int nloc = min(256, n - node0);
    int ebeg = bboff[b], eend = bboff[b + 1];
    int ne = eend - ebeg;
    lcnt[t] = 0;
    __syncthreads();
    bool staged = (ne <= ECAP);
    if (staged) {
        for (int i = t; i < ne; i += 256) {
            int e = binned[ebeg + i];
            se[i] = e;
            atomicAdd(&lcnt[e & 255], 1);
        }
    } else {
        for (int i = t; i < ne; i += 256)
            atomicAdd(&lcnt[binned[ebeg + i] & 255], 1);
    }
    __syncthreads();
    int myc = (t < nloc) ? lcnt[t] : 0;
    ssc[t] = myc;
    __syncthreads();
    for (int o = 1; o < 256; o <<= 1) {
        int add = (t >= o) ? ssc[t - o] : 0;
        __syncthreads();
        ssc[t] += add;
        __syncthreads();
    }
    int excl = ssc[t] - myc;
    if (t < nloc) {
        cnt[node0 + t] = myc;
        dinv[node0 + t] = rsqrtf((float)(myc + 1));
        cursor[node0 + t] = ebeg + excl;   // cursor = start of node's list
        lcur[t] = excl;
    }
    __syncthreads();
    if (staged) {
        for (int i = t; i < ne; i += 256) {
            int e = se[i];
            int pos = atomicAdd(&lcur[e & 255], 1);
            csr_src[ebeg + pos] = ((unsigned int)e) >> 8;
        }
    } else {
        for (int i = t; i < ne; i += 256) {
            int e = binned[ebeg + i];
            int pos = atomicAdd(&lcur[e & 255], 1);
            csr_src[ebeg + pos] = ((unsigned int)e) >> 8;
        }
    }
}

// ---- W pre-pack (both layers) + pooled zero-init ----
__global__ __launch_bounds__(256) void wprep2(const float* __restrict__ W1,
                                              const float* __restrict__ W2,
                                              unsigned short* __restrict__ Wbf1,
                                              unsigned short* __restrict__ Wbf2,
                                              float* __restrict__ pooled) {
    int tid = blockIdx.x * 256 + threadIdx.x;   // 32768 threads
    if (tid < FEAT) pooled[tid] = 0.0f;
    const float* W = (tid < 16384) ? W1 : W2;
    unsigned short* O = (tid < 16384) ? Wbf1 : Wbf2;
    int id = tid & 16383;
    int chunk = id >> 3, j = id & 7;
    int kb = chunk >> 7, nn = chunk & 127;
    O[id] = f2bf(W[(kb * 8 + j) * FEAT + nn]);
}

// ---- MFMA GEMM: gout[N][128](fp8) = bf16(X) @ Wbf * dinv[row] ----
// AFP32=true: X is fp32 rows. AFP32=false: X is fp8 e4m3 rows (exact->bf16).
template <bool AFP32>
__global__ __launch_bounds__(256) void gemm_mfma(const void* __restrict__ Xv,
                                                 const unsigned short* __restrict__ Wbf,
                                                 const float* __restrict__ dinv,
                                                 unsigned char* __restrict__ gout,
                                                 int n) {
    int wave = threadIdx.x >> 6, lane = threadIdx.x & 63;
    int m0 = blockIdx.x * 64 + wave * 16;
    if (m0 >= n) return;
    int col = lane & 15, quad = lane >> 4;
    int mc = min(m0 + col, n - 1);

    short8 afr[4];
    if (AFP32) {
        const float* X = (const float*)Xv;
        const float* xr = X + (size_t)mc * FEAT + quad * 8;
#pragma unroll
        for (int ks = 0; ks < 4; ks++) {
            float4 lo = *(const float4*)(xr + ks * 32);
            float4 hi = *(const float4*)(xr + ks * 32 + 4);
            short8 a;
            a[0] = (short)f2bf(lo.x); a[1] = (short)f2bf(lo.y);
            a[2] = (short)f2bf(lo.z); a[3] = (short)f2bf(lo.w);
            a[4] = (short)f2bf(hi.x); a[5] = (short)f2bf(hi.y);
            a[6] = (short)f2bf(hi.z); a[7] = (short)f2bf(hi.w);
            afr[ks] = a;
        }
    } else {
        const unsigned char* X8 = (const unsigned char*)Xv;
        const unsigned char* xr = X8 + (size_t)mc * FEAT + quad * 8;
#pragma unroll
        for (int ks = 0; ks < 4; ks++) {
            uint2 u2 = *(const uint2*)(xr + ks * 32);
            floatx2 p0 = fp8x2_dec(u2.x);
            floatx2 p1 = fp8x2_dec_hi(u2.x);
            floatx2 p2 = fp8x2_dec(u2.y);
            floatx2 p3 = fp8x2_dec_hi(u2.y);
            short8 a;
            a[0] = (short)f2bf(p0.x); a[1] = (short)f2bf(p0.y);
            a[2] = (short)f2bf(p1.x); a[3] = (short)f2bf(p1.y);
            a[4] = (short)f2bf(p2.x); a[5] = (short)f2bf(p2.y);
            a[6] = (short)f2bf(p3.x); a[7] = (short)f2bf(p3.y);
            afr[ks] = a;
        }
    }

    float dvr[4];
#pragma unroll
    for (int r = 0; r < 4; r++)
        dvr[r] = dinv[min(m0 + quad * 4 + r, n - 1)];

    const int4* Wb = (const int4*)Wbf;
#pragma unroll
    for (int nt = 0; nt < 8; nt++) {
        float4v acc = {0.f, 0.f, 0.f, 0.f};
#pragma unroll
        for (int ks = 0; ks < 4; ks++) {
            int kb = ks * 4 + quad;
            I4S8 u; u.i = Wb[kb * FEAT + nt * 16 + col];
            acc = __builtin_amdgcn_mfma_f32_16x16x32_bf16(afr[ks], u.s, acc, 0, 0, 0);
        }
#pragma unroll
        for (int r = 0; r < 4; r++) {
            int row = m0 + quad * 4 + r;
            if (row < n)
                gout[(size_t)row * FEAT + nt * 16 + col] = fp8enc(acc[r] * dvr[r]);
        }
    }
}

// ---- gather-sum core for one node (fp8 rows, 2 feats/lane) ----
// 32-bit unsigned byte-offset addressing against wave-uniform bases:
// gather offB = (src<<7)|lane2 (1 VALU), idx offB = jb + 4k (1 VALU, literal).
static __device__ inline void gather_node(const unsigned char* __restrict__ csrB,
                                          const unsigned char* __restrict__ gb,
                                          int beg, int end, unsigned node,
                                          unsigned lane2, float& sx, float& sy) {
    floatx2 a0 = fp8x2_dec(*(const unsigned short*)(gb + ((node << 7) | lane2)));
    floatx2 a1 = {0.f, 0.f}, a2 = {0.f, 0.f}, a3 = {0.f, 0.f};
    int j = beg;
    for (; j + 15 < end; j += 16) {
        unsigned jb = (unsigned)j << 2;
        unsigned sIdx[16];
#pragma unroll
        for (int k = 0; k < 16; k++)
            sIdx[k] = *(const unsigned*)(csrB + (jb + 4u * (unsigned)k));
        unsigned short uu[16];
#pragma unroll
        for (int k = 0; k < 16; k++)
            uu[k] = *(const unsigned short*)(gb + ((sIdx[k] << 7) | lane2));
#pragma unroll
        for (int k = 0; k < 16; k += 4) {
            a0 += fp8x2_dec(uu[k]);
            a1 += fp8x2_dec(uu[k + 1]);
            a2 += fp8x2_dec(uu[k + 2]);
            a3 += fp8x2_dec(uu[k + 3]);
        }
    }
    for (; j + 3 < end; j += 4) {
        unsigned jb = (unsigned)j << 2;
        unsigned s0 = *(const unsigned*)(csrB + jb);
        unsigned s1 = *(const unsigned*)(csrB + (jb + 4u));
        unsigned s2 = *(const unsigned*)(csrB + (jb + 8u));
        unsigned s3 = *(const unsigned*)(csrB + (jb + 12u));
        a0 += fp8x2_dec(*(const unsigned short*)(gb + ((s0 << 7) | lane2)));
        a1 += fp8x2_dec(*(const unsigned short*)(gb + ((s1 << 7) | lane2)));
        a2 += fp8x2_dec(*(const unsigned short*)(gb + ((s2 << 7) | lane2)));
        a3 += fp8x2_dec(*(const unsigned short*)(gb + ((s3 << 7) | lane2)));
    }
    for (; j < end; j++) {
        unsigned s0 = *(const unsigned*)(csrB + ((unsigned)j << 2));
        a0 += fp8x2_dec(*(const unsigned short*)(gb + ((s0 << 7) | lane2)));
    }
    floatx2 a = (a0 + a1) + (a2 + a3);
    sx = a.x;
    sy = a.y;
}

// ---- agg: CSR gather + bias + relu -> fp8 rows (1 node per wave) ----
__global__ __launch_bounds__(256) void agg_csr(const int* __restrict__ cursor,
                                               const int* __restrict__ cnt,
                                               const int* __restrict__ csr_src,
                                               const unsigned char* __restrict__ gbuf,
                                               const float* __restrict__ dinv,
                                               const float* __restrict__ bias,
                                               unsigned short* __restrict__ outb,
                                               int n) {
    int node = blockIdx.x * 4 + (threadIdx.x >> 6);
    if (node >= n) return;
    unsigned lane = threadIdx.x & 63;
    unsigned lane2 = lane << 1;
    int beg = cursor[node];
    int end = beg + cnt[node];
    float sx, sy;
    gather_node((const unsigned char*)csr_src, gbuf, beg, end,
                (unsigned)node, lane2, sx, sy);
    float dv = dinv[node];
    float2 bv = ((const float2*)bias)[lane];
    float rx = fmaxf(sx * dv + bv.x, 0.0f);
    float ry = fmaxf(sy * dv + bv.y, 0.0f);
    outb[(((unsigned)node) << 6) | lane] = fp8x2_enc(rx, ry);
}

// ---- mean pool stage 1 (fp8 input, 1024 blocks) ----
__global__ __launch_bounds__(256) void pool_kernel(const unsigned char* __restrict__ a,
                                                   float* __restrict__ pooled, int n) {
    int tid = blockIdx.x * 256 + threadIdx.x;  // 1024 blocks -> 262144 threads
    unsigned f = (unsigned)tid & 127u;
    int i0 = tid >> 7;  // 0..2047
    float s = 0.0f;
    for (int i = i0; i < n; i += 2048)
        s += fp8x2_dec((unsigned int)a[(((unsigned)i) << 7) | f]).x;
    atomicAdd(&pooled[f], s);
}

// ---- final: out[c] = (pooled/N) . Wc[:,c] + bc[c] ----
__global__ __launch_bounds__(128) void final_kernel(const float* __restrict__ pooled,
                                                    const float* __restrict__ Wc,
                                                    const float* __restrict__ bc,
                                                    float* __restrict__ out,
                                                    int n, int C) {
    __shared__ float p[FEAT];
    int t = threadIdx.x;
    p[t] = pooled[t] * (1.0f / (float)n);
    __syncthreads();
    if (t < C) {
        float acc = bc[t];
        for (int h = 0; h < FEAT; h++)
            acc += p[h] * Wc[h * C + t];
        out[t] = acc;
    }
}

extern "C" void kernel_launch(void* const* d_in, const int* in_sizes, int n_in,
                              void* d_out, int out_size, void* d_ws, size_t ws_size,
                              hipStream_t stream) {
    const float* x  = (const float*)d_in[0];
    const int*   ei = (const int*)d_in[1];
    const float* W1 = (const float*)d_in[2];
    const float* b1 = (const float*)d_in[3];
    const float* W2 = (const float*)d_in[4];
    const float* b2 = (const float*)d_in[5];
    const float* Wc = (const float*)d_in[6];
    const float* bc = (const float*)d_in[7];

    const int N = in_sizes[0] / FEAT;        // 100000
    const int E = in_sizes[1] / 2;           // 1600000
    const int C = out_size;                  // 32
    const int* srcI = ei;
    const int* dstI = ei + E;
    const int NC = (E + CHUNK - 1) / CHUNK;  // edge chunks (391, <= 512)
    const int NBK = (N + 255) >> 8;          // node buckets (391, <= MAXBUCK)

    // workspace carve (256B aligned)
    auto align256 = [](size_t v) { return (v + 255) & ~(size_t)255; };
    char* w = (char*)d_ws;
    int*            cnt     = (int*)w;            w += align256((size_t)N * 4);
    float*          dinv    = (float*)w;          w += align256((size_t)N * 4);
    int*            cursor  = (int*)w;            w += align256((size_t)N * 4);
    int*            csr_src = (int*)w;            w += align256((size_t)E * 4);
    int*            binned  = (int*)w;            w += align256((size_t)E * 4);
    int*            hist    = (int*)w;            w += align256((size_t)NBK * NC * 4);
    int*            hoff    = (int*)w;            w += align256((size_t)NBK * NC * 4);
    int*            btot    = (int*)w;            w += align256((size_t)NBK * 4);
    int*            bboff   = (int*)w;            w += align256((size_t)(NBK + 1) * 4);
    unsigned short* Wbf1    = (unsigned short*)w; w += align256((size_t)FEAT * FEAT * 2);
    unsigned short* Wbf2    = (unsigned short*)w; w += align256((size_t)FEAT * FEAT * 2);
    unsigned char*  gbuf    = (unsigned char*)w;  w += align256((size_t)N * FEAT);
    unsigned char*  bufA    = (unsigned char*)w;  w += align256((size_t)N * FEAT);
    float*          pooled  = (float*)w;          w += align256((size_t)FEAT * 4);

    // W pre-pack (both layers) + pooled zero
    wprep2<<<128, 256, 0, stream>>>(W1, W2, Wbf1, Wbf2, pooled);

    // ---- atomic-free CSR build (all kernels >= 391 blocks except bscan) ----
    hist2<<<NC, 256, 0, stream>>>(dstI, hist, E, NC, NBK);
    rowsum_k<<<NBK, 256, 0, stream>>>(hist, btot, NC);
    bscan_k<<<1, 512, 0, stream>>>(btot, bboff, NBK);
    rowoff_k<<<NBK, 512, 0, stream>>>(hist, bboff, hoff, NC);
    fill2<<<NC, 256, 0, stream>>>(srcI, dstI, hoff, binned, E, NC, NBK);
    bucket_scat<<<NBK, 256, 0, stream>>>(binned, bboff, cnt, dinv, cursor, csr_src, N);

    const int gGemm = (N + 63) / 64;
    const int gAgg = (N + 3) / 4;

    // ---- layer 1 ----
    gemm_mfma<true><<<gGemm, 256, 0, stream>>>(x, Wbf1, dinv, gbuf, N);
    agg_csr<<<gAgg, 256, 0, stream>>>(cursor, cnt, csr_src, gbuf, dinv, b1,
                                      (unsigned short*)bufA, N);

    // ---- layer 2 ----
    gemm_mfma<false><<<gGemm, 256, 0, stream>>>(bufA, Wbf2, dinv, gbuf, N);
    agg_csr<<<gAgg, 256, 0, stream>>>(cursor, cnt, csr_src, gbuf, dinv, b2,
                                      (unsigned short*)bufA, N);

    // ---- pool + classifier ----
    pool_kernel<<<1024, 256, 0, stream>>>(bufA, pooled, N);
    final_kernel<<<1, 128, 0, stream>>>(pooled, Wc, bc, (float*)d_out, N, C);
}

// Round 6
// 312.347 us; speedup vs baseline: 1.9064x; 1.1355x over previous
//
#include <hip/hip_runtime.h>
#include <hip/hip_bf16.h>

// GCN: h1 = relu(Agg(x@W1)+b1); h2 = relu(Agg(h1@W2)+b2); out = mean(h2)@Wc + bc
// Agg via CSR gather; g = (X@W)*dinv stored OCP fp8 e4m3 (128B node-major rows).
// r5: agg addressing = 32-bit unsigned byte offsets vs wave-uniform SGPR base
// (saddr form): gather offB=(src<<7)|(lane<<1), idx=jb+4k. agg ~56us (was 64).
// r6: pool_kernel was 62us -- NOT memory (12.8MB read @120GB/s) but global
// atomicAdd serialization: WRITE_SIZE=1024KB = 262144 x 4B write-through RMWs
// onto 8 cache lines (~32k serial RMW/line ~= 65us). Fix: per-block partial
// sums (no atomics) + reduction folded into final_kernel. Vectorized uint2
// (8 x fp8) pool loads: wave = 4 rows x 128B = 512B contiguous per instr.
// r1-r3 lessons (plane-sharded L2-resident gather): FETCH drops 89.6->37MB but
// 32B plane rows double L2 transactions per byte and lengthen the dependent
// chain -> strictly worse than node-major 128B rows.
// r4: activations h1/h2 fp8 e4m3 (write-invisible in agg -> agg is
// fetch-latency+VALU bound, confirmed).
// CSR build atomic-free; ALL build kernels >= 391 blocks (r11: narrow build
// kernels were width-starved, ~270us invisible tail).
// GEMMs: mfma_f32_16x16x32_bf16, LDS-free, W pre-packed to k-block layout.

#define FEAT 128
#define CHUNK 4096      // edges per chunk (391 chunks)
#define MAXBUCK 512     // max node-buckets (N <= 131072); also NC cap
#define ECAP 12288      // LDS edge staging cap in bucket_scat (48 KB of int)
#define PBLK 512        // pool stage-1 blocks

typedef __attribute__((ext_vector_type(8))) short short8;
typedef __attribute__((ext_vector_type(4))) float float4v;
typedef __attribute__((ext_vector_type(2))) float floatx2;

union I4S8 { int4 i; short8 s; };

static __device__ inline unsigned short f2bf(float f) {
    union { __hip_bfloat16 h; unsigned short u; } cv;
    cv.h = __float2bfloat16(f);
    return cv.u;
}

// ---- OCP fp8 e4m3 helpers ----
static __device__ inline floatx2 fp8x2_dec(unsigned int u) {
#if __has_builtin(__builtin_amdgcn_cvt_pk_f32_fp8)
    return __builtin_amdgcn_cvt_pk_f32_fp8((int)u, false);
#else
    floatx2 r;
    unsigned int b0 = u & 0xFFu, b1 = (u >> 8) & 0xFFu;
    r.x = __uint_as_float(((b0 & 0x80u) << 24) | ((b0 & 0x7Fu) << 20)) * 0x1p+120f;
    r.y = __uint_as_float(((b1 & 0x80u) << 24) | ((b1 & 0x7Fu) << 20)) * 0x1p+120f;
    return r;
#endif
}

static __device__ inline floatx2 fp8x2_dec_hi(unsigned int u) {
#if __has_builtin(__builtin_amdgcn_cvt_pk_f32_fp8)
    return __builtin_amdgcn_cvt_pk_f32_fp8((int)u, true);
#else
    return fp8x2_dec(u >> 16);
#endif
}

// pack two floats -> two fp8 e4m3 bytes (low word)
static __device__ inline unsigned short fp8x2_enc(float x, float y) {
#if __has_builtin(__builtin_amdgcn_cvt_pk_fp8_f32)
    return (unsigned short)(__builtin_amdgcn_cvt_pk_fp8_f32(x, y, 0, false) & 0xFFFF);
#else
    auto enc1 = [](float f) -> unsigned int {
        unsigned int u = __float_as_uint(f);
        unsigned int s = (u >> 24) & 0x80u;
        float a = fabsf(f);
        a = fminf(a, 448.0f);
        unsigned int code;
        if (a < 0.015625f) {
            code = (unsigned int)(int)rintf(a * 512.0f);
        } else {
            unsigned int au = __float_as_uint(a);
            unsigned int r = au + 0x0007FFFFu + ((au >> 20) & 1u);
            unsigned int e = (r >> 23) - 120u;
            unsigned int m = (r >> 20) & 7u;
            code = (e << 3) | m;
            if (code > 0x7Eu) code = 0x7Eu;
        }
        return code | s;
    };
    return (unsigned short)(enc1(x) | (enc1(y) << 8));
#endif
}

static __device__ inline unsigned char fp8enc(float f) {
#if __has_builtin(__builtin_amdgcn_cvt_pk_fp8_f32)
    return (unsigned char)(__builtin_amdgcn_cvt_pk_fp8_f32(f, 0.0f, 0, false) & 0xFF);
#else
    return (unsigned char)(fp8x2_enc(f, 0.0f) & 0xFF);
#endif
}

// ---- build phase 1: per-chunk histogram over node buckets (dst>>8) ----
__global__ __launch_bounds__(256) void hist2(const int* __restrict__ dst,
                                             int* __restrict__ hist,
                                             int nE, int NC, int nbuck) {
    __shared__ int h[MAXBUCK];
    int c = blockIdx.x, t = threadIdx.x;
    for (int i = t; i < nbuck; i += 256) h[i] = 0;
    __syncthreads();
    int beg = c * CHUNK, end = min(nE, beg + CHUNK);
    for (int e = beg + t; e < end; e += 256)
        atomicAdd(&h[dst[e] >> 8], 1);
    __syncthreads();
    for (int i = t; i < nbuck; i += 256) hist[i * NC + c] = h[i];
}

// ---- phase 2a: per-bucket totals (wide: one block per bucket) ----
__global__ __launch_bounds__(256) void rowsum_k(const int* __restrict__ hist,
                                                int* __restrict__ btot, int NC) {
    __shared__ int red[256];
    int b = blockIdx.x, t = threadIdx.x;
    int s = 0;
    for (int c = t; c < NC; c += 256) s += hist[b * NC + c];
    red[t] = s;
    __syncthreads();
    for (int o = 128; o > 0; o >>= 1) {
        if (t < o) red[t] += red[t + o];
        __syncthreads();
    }
    if (t == 0) btot[b] = red[0];
}

// ---- phase 2b: exclusive scan of bucket totals (nbuck <= 512) ----
__global__ __launch_bounds__(512) void bscan_k(const int* __restrict__ btot,
                                               int* __restrict__ bboff, int nbuck) {
    __shared__ int sc[512];
    int t = threadIdx.x;
    int v = (t < nbuck) ? btot[t] : 0;
    sc[t] = v;
    __syncthreads();
    for (int o = 1; o < 512; o <<= 1) {
        int add = (t >= o) ? sc[t - o] : 0;
        __syncthreads();
        sc[t] += add;
        __syncthreads();
    }
    if (t < nbuck) {
        bboff[t] = sc[t] - v;
        if (t == nbuck - 1) bboff[nbuck] = sc[t];
    }
}

// ---- phase 2c: per-(bucket,chunk) offsets (wide: block-parallel scan, NC<=512) ----
__global__ __launch_bounds__(512) void rowoff_k(const int* __restrict__ hist,
                                                const int* __restrict__ bboff,
                                                int* __restrict__ hoff, int NC) {
    __shared__ int sc[512];
    int b = blockIdx.x, t = threadIdx.x;
    int v = (t < NC) ? hist[b * NC + t] : 0;
    sc[t] = v;
    __syncthreads();
    for (int o = 1; o < 512; o <<= 1) {
        int add = (t >= o) ? sc[t - o] : 0;
        __syncthreads();
        sc[t] += add;
        __syncthreads();
    }
    if (t < NC) hoff[b * NC + t] = bboff[b] + sc[t] - v;
}

// ---- phase 3: pack (src<<8|dloc) bucket-grouped; LDS cursors ----
__global__ __launch_bounds__(256) void fill2(const int* __restrict__ src,
                                             const int* __restrict__ dst,
                                             const int* __restrict__ off,
                                             int* __restrict__ binned,
                                             int nE, int NC, int nbuck) {
    __shared__ int cur[MAXBUCK];
    int c = blockIdx.x, t = threadIdx.x;
    for (int i = t; i < nbuck; i += 256) cur[i] = off[i * NC + c];
    __syncthreads();
    int beg = c * CHUNK, end = min(nE, beg + CHUNK);
    for (int e = beg + t; e < end; e += 256) {
        int d = dst[e];
        int pos = atomicAdd(&cur[d >> 8], 1);
        binned[pos] = (src[e] << 8) | (d & 255);
    }
}

// ---- phase 4: per-bucket count + dinv + cursor + csr scatter (all LDS) ----
__global__ __launch_bounds__(256) void bucket_scat(const int* __restrict__ binned,
                                                   const int* __restrict__ bboff,
                                                   int* __restrict__ cnt,
                                                   float* __restrict__ dinv,
                                                   int* __restrict__ cursor,
                                                   int* __restrict__ csr_src, int n) {
    __shared__ int se[ECAP];
    __shared__ int lcnt[256];
    __shared__ int lcur[256];
    __shared__ int ssc[256];
    int b = blockIdx.x, t = threadIdx.x;
    int node0 = b << 8;
    int nloc = min(256, n - node0);
    int ebeg = bboff[b], eend = bboff[b + 1];
    int ne = eend - ebeg;
    lcnt[t] = 0;
    __syncthreads();
    bool staged = (ne <= ECAP);
    if (staged) {
        for (int i = t; i < ne; i += 256) {
            int e = binned[ebeg + i];
            se[i] = e;
            atomicAdd(&lcnt[e & 255], 1);
        }
    } else {
        for (int i = t; i < ne; i += 256)
            atomicAdd(&lcnt[binned[ebeg + i] & 255], 1);
    }
    __syncthreads();
    int myc = (t < nloc) ? lcnt[t] : 0;
    ssc[t] = myc;
    __syncthreads();
    for (int o = 1; o < 256; o <<= 1) {
        int add = (t >= o) ? ssc[t - o] : 0;
        __syncthreads();
        ssc[t] += add;
        __syncthreads();
    }
    int excl = ssc[t] - myc;
    if (t < nloc) {
        cnt[node0 + t] = myc;
        dinv[node0 + t] = rsqrtf((float)(myc + 1));
        cursor[node0 + t] = ebeg + excl;   // cursor = start of node's list
        lcur[t] = excl;
    }
    __syncthreads();
    if (staged) {
        for (int i = t; i < ne; i += 256) {
            int e = se[i];
            int pos = atomicAdd(&lcur[e & 255], 1);
            csr_src[ebeg + pos] = ((unsigned int)e) >> 8;
        }
    } else {
        for (int i = t; i < ne; i += 256) {
            int e = binned[ebeg + i];
            int pos = atomicAdd(&lcur[e & 255], 1);
            csr_src[ebeg + pos] = ((unsigned int)e) >> 8;
        }
    }
}

// ---- W pre-pack (both layers) ----
__global__ __launch_bounds__(256) void wprep2(const float* __restrict__ W1,
                                              const float* __restrict__ W2,
                                              unsigned short* __restrict__ Wbf1,
                                              unsigned short* __restrict__ Wbf2) {
    int tid = blockIdx.x * 256 + threadIdx.x;   // 32768 threads
    const float* W = (tid < 16384) ? W1 : W2;
    unsigned short* O = (tid < 16384) ? Wbf1 : Wbf2;
    int id = tid & 16383;
    int chunk = id >> 3, j = id & 7;
    int kb = chunk >> 7, nn = chunk & 127;
    O[id] = f2bf(W[(kb * 8 + j) * FEAT + nn]);
}

// ---- MFMA GEMM: gout[N][128](fp8) = bf16(X) @ Wbf * dinv[row] ----
// AFP32=true: X is fp32 rows. AFP32=false: X is fp8 e4m3 rows (exact->bf16).
template <bool AFP32>
__global__ __launch_bounds__(256) void gemm_mfma(const void* __restrict__ Xv,
                                                 const unsigned short* __restrict__ Wbf,
                                                 const float* __restrict__ dinv,
                                                 unsigned char* __restrict__ gout,
                                                 int n) {
    int wave = threadIdx.x >> 6, lane = threadIdx.x & 63;
    int m0 = blockIdx.x * 64 + wave * 16;
    if (m0 >= n) return;
    int col = lane & 15, quad = lane >> 4;
    int mc = min(m0 + col, n - 1);

    short8 afr[4];
    if (AFP32) {
        const float* X = (const float*)Xv;
        const float* xr = X + (size_t)mc * FEAT + quad * 8;
#pragma unroll
        for (int ks = 0; ks < 4; ks++) {
            float4 lo = *(const float4*)(xr + ks * 32);
            float4 hi = *(const float4*)(xr + ks * 32 + 4);
            short8 a;
            a[0] = (short)f2bf(lo.x); a[1] = (short)f2bf(lo.y);
            a[2] = (short)f2bf(lo.z); a[3] = (short)f2bf(lo.w);
            a[4] = (short)f2bf(hi.x); a[5] = (short)f2bf(hi.y);
            a[6] = (short)f2bf(hi.z); a[7] = (short)f2bf(hi.w);
            afr[ks] = a;
        }
    } else {
        const unsigned char* X8 = (const unsigned char*)Xv;
        const unsigned char* xr = X8 + (size_t)mc * FEAT + quad * 8;
#pragma unroll
        for (int ks = 0; ks < 4; ks++) {
            uint2 u2 = *(const uint2*)(xr + ks * 32);
            floatx2 p0 = fp8x2_dec(u2.x);
            floatx2 p1 = fp8x2_dec_hi(u2.x);
            floatx2 p2 = fp8x2_dec(u2.y);
            floatx2 p3 = fp8x2_dec_hi(u2.y);
            short8 a;
            a[0] = (short)f2bf(p0.x); a[1] = (short)f2bf(p0.y);
            a[2] = (short)f2bf(p1.x); a[3] = (short)f2bf(p1.y);
            a[4] = (short)f2bf(p2.x); a[5] = (short)f2bf(p2.y);
            a[6] = (short)f2bf(p3.x); a[7] = (short)f2bf(p3.y);
            afr[ks] = a;
        }
    }

    float dvr[4];
#pragma unroll
    for (int r = 0; r < 4; r++)
        dvr[r] = dinv[min(m0 + quad * 4 + r, n - 1)];

    const int4* Wb = (const int4*)Wbf;
#pragma unroll
    for (int nt = 0; nt < 8; nt++) {
        float4v acc = {0.f, 0.f, 0.f, 0.f};
#pragma unroll
        for (int ks = 0; ks < 4; ks++) {
            int kb = ks * 4 + quad;
            I4S8 u; u.i = Wb[kb * FEAT + nt * 16 + col];
            acc = __builtin_amdgcn_mfma_f32_16x16x32_bf16(afr[ks], u.s, acc, 0, 0, 0);
        }
#pragma unroll
        for (int r = 0; r < 4; r++) {
            int row = m0 + quad * 4 + r;
            if (row < n)
                gout[(size_t)row * FEAT + nt * 16 + col] = fp8enc(acc[r] * dvr[r]);
        }
    }
}

// ---- gather-sum core for one node (fp8 rows, 2 feats/lane) ----
// 32-bit unsigned byte-offset addressing against wave-uniform bases:
// gather offB = (src<<7)|lane2 (1 VALU), idx offB = jb + 4k (1 VALU, literal).
static __device__ inline void gather_node(const unsigned char* __restrict__ csrB,
                                          const unsigned char* __restrict__ gb,
                                          int beg, int end, unsigned node,
                                          unsigned lane2, float& sx, float& sy) {
    floatx2 a0 = fp8x2_dec(*(const unsigned short*)(gb + ((node << 7) | lane2)));
    floatx2 a1 = {0.f, 0.f}, a2 = {0.f, 0.f}, a3 = {0.f, 0.f};
    int j = beg;
    for (; j + 15 < end; j += 16) {
        unsigned jb = (unsigned)j << 2;
        unsigned sIdx[16];
#pragma unroll
        for (int k = 0; k < 16; k++)
            sIdx[k] = *(const unsigned*)(csrB + (jb + 4u * (unsigned)k));
        unsigned short uu[16];
#pragma unroll
        for (int k = 0; k < 16; k++)
            uu[k] = *(const unsigned short*)(gb + ((sIdx[k] << 7) | lane2));
#pragma unroll
        for (int k = 0; k < 16; k += 4) {
            a0 += fp8x2_dec(uu[k]);
            a1 += fp8x2_dec(uu[k + 1]);
            a2 += fp8x2_dec(uu[k + 2]);
            a3 += fp8x2_dec(uu[k + 3]);
        }
    }
    for (; j + 3 < end; j += 4) {
        unsigned jb = (unsigned)j << 2;
        unsigned s0 = *(const unsigned*)(csrB + jb);
        unsigned s1 = *(const unsigned*)(csrB + (jb + 4u));
        unsigned s2 = *(const unsigned*)(csrB + (jb + 8u));
        unsigned s3 = *(const unsigned*)(csrB + (jb + 12u));
        a0 += fp8x2_dec(*(const unsigned short*)(gb + ((s0 << 7) | lane2)));
        a1 += fp8x2_dec(*(const unsigned short*)(gb + ((s1 << 7) | lane2)));
        a2 += fp8x2_dec(*(const unsigned short*)(gb + ((s2 << 7) | lane2)));
        a3 += fp8x2_dec(*(const unsigned short*)(gb + ((s3 << 7) | lane2)));
    }
    for (; j < end; j++) {
        unsigned s0 = *(const unsigned*)(csrB + ((unsigned)j << 2));
        a0 += fp8x2_dec(*(const unsigned short*)(gb + ((s0 << 7) | lane2)));
    }
    floatx2 a = (a0 + a1) + (a2 + a3);
    sx = a.x;
    sy = a.y;
}

// ---- agg: CSR gather + bias + relu -> fp8 rows (1 node per wave) ----
__global__ __launch_bounds__(256) void agg_csr(const int* __restrict__ cursor,
                                               const int* __restrict__ cnt,
                                               const int* __restrict__ csr_src,
                                               const unsigned char* __restrict__ gbuf,
                                               const float* __restrict__ dinv,
                                               const float* __restrict__ bias,
                                               unsigned short* __restrict__ outb,
                                               int n) {
    int node = blockIdx.x * 4 + (threadIdx.x >> 6);
    if (node >= n) return;
    unsigned lane = threadIdx.x & 63;
    unsigned lane2 = lane << 1;
    int beg = cursor[node];
    int end = beg + cnt[node];
    float sx, sy;
    gather_node((const unsigned char*)csr_src, gbuf, beg, end,
                (unsigned)node, lane2, sx, sy);
    float dv = dinv[node];
    float2 bv = ((const float2*)bias)[lane];
    float rx = fmaxf(sx * dv + bv.x, 0.0f);
    float ry = fmaxf(sy * dv + bv.y, 0.0f);
    outb[(((unsigned)node) << 6) | lane] = fp8x2_enc(rx, ry);
}

// ---- mean pool stage 1: per-block partial sums, NO global atomics ----
// thread: fg = t&15 (8 feats via uint2), rg = t>>4 (row in block group).
// wave = 4 consecutive rows x 128B = 512B contiguous per load instruction.
__global__ __launch_bounds__(256) void pool_kernel(const unsigned char* __restrict__ a,
                                                   float* __restrict__ partial, int n) {
    __shared__ float red[16][132];   // +4 pad
    int t = threadIdx.x, b = blockIdx.x;
    int fg = t & 15;
    int rg = t >> 4;
    unsigned fb = (unsigned)fg << 3;             // feature byte offset
    floatx2 s01 = {0.f, 0.f}, s23 = {0.f, 0.f}, s45 = {0.f, 0.f}, s67 = {0.f, 0.f};
    for (int i = (b << 4) | rg; i < n; i += PBLK * 16) {
        uint2 u2 = *(const uint2*)(a + (((unsigned)i << 7) | fb));
        s01 += fp8x2_dec(u2.x);
        s23 += fp8x2_dec_hi(u2.x);
        s45 += fp8x2_dec(u2.y);
        s67 += fp8x2_dec_hi(u2.y);
    }
    red[rg][fb + 0] = s01.x; red[rg][fb + 1] = s01.y;
    red[rg][fb + 2] = s23.x; red[rg][fb + 3] = s23.y;
    red[rg][fb + 4] = s45.x; red[rg][fb + 5] = s45.y;
    red[rg][fb + 6] = s67.x; red[rg][fb + 7] = s67.y;
    __syncthreads();
    if (t < FEAT) {
        float s = 0.0f;
#pragma unroll
        for (int k = 0; k < 16; k++) s += red[k][t];
        partial[b * FEAT + t] = s;
    }
}

// ---- final: reduce partials; out[c] = (pooled/N) . Wc[:,c] + bc[c] ----
__global__ __launch_bounds__(128) void final_kernel(const float* __restrict__ partial,
                                                    const float* __restrict__ Wc,
                                                    const float* __restrict__ bc,
                                                    float* __restrict__ out,
                                                    int n, int C) {
    __shared__ float p[FEAT];
    int t = threadIdx.x;
    float s = 0.0f;
    for (int b = 0; b < PBLK; b++) s += partial[b * FEAT + t];
    p[t] = s * (1.0f / (float)n);
    __syncthreads();
    if (t < C) {
        float acc = bc[t];
        for (int h = 0; h < FEAT; h++)
            acc += p[h] * Wc[h * C + t];
        out[t] = acc;
    }
}

extern "C" void kernel_launch(void* const* d_in, const int* in_sizes, int n_in,
                              void* d_out, int out_size, void* d_ws, size_t ws_size,
                              hipStream_t stream) {
    const float* x  = (const float*)d_in[0];
    const int*   ei = (const int*)d_in[1];
    const float* W1 = (const float*)d_in[2];
    const float* b1 = (const float*)d_in[3];
    const float* W2 = (const float*)d_in[4];
    const float* b2 = (const float*)d_in[5];
    const float* Wc = (const float*)d_in[6];
    const float* bc = (const float*)d_in[7];

    const int N = in_sizes[0] / FEAT;        // 100000
    const int E = in_sizes[1] / 2;           // 1600000
    const int C = out_size;                  // 32
    const int* srcI = ei;
    const int* dstI = ei + E;
    const int NC = (E + CHUNK - 1) / CHUNK;  // edge chunks (391, <= 512)
    const int NBK = (N + 255) >> 8;          // node buckets (391, <= MAXBUCK)

    // workspace carve (256B aligned)
    auto align256 = [](size_t v) { return (v + 255) & ~(size_t)255; };
    char* w = (char*)d_ws;
    int*            cnt     = (int*)w;            w += align256((size_t)N * 4);
    float*          dinv    = (float*)w;          w += align256((size_t)N * 4);
    int*            cursor  = (int*)w;            w += align256((size_t)N * 4);
    int*            csr_src = (int*)w;            w += align256((size_t)E * 4);
    int*            binned  = (int*)w;            w += align256((size_t)E * 4);
    int*            hist    = (int*)w;            w += align256((size_t)NBK * NC * 4);
    int*            hoff    = (int*)w;            w += align256((size_t)NBK * NC * 4);
    int*            btot    = (int*)w;            w += align256((size_t)NBK * 4);
    int*            bboff   = (int*)w;            w += align256((size_t)(NBK + 1) * 4);
    unsigned short* Wbf1    = (unsigned short*)w; w += align256((size_t)FEAT * FEAT * 2);
    unsigned short* Wbf2    = (unsigned short*)w; w += align256((size_t)FEAT * FEAT * 2);
    unsigned char*  gbuf    = (unsigned char*)w;  w += align256((size_t)N * FEAT);
    unsigned char*  bufA    = (unsigned char*)w;  w += align256((size_t)N * FEAT);
    float*          partial = (float*)w;          w += align256((size_t)PBLK * FEAT * 4);

    // W pre-pack (both layers)
    wprep2<<<128, 256, 0, stream>>>(W1, W2, Wbf1, Wbf2);

    // ---- atomic-free CSR build (all kernels >= 391 blocks except bscan) ----
    hist2<<<NC, 256, 0, stream>>>(dstI, hist, E, NC, NBK);
    rowsum_k<<<NBK, 256, 0, stream>>>(hist, btot, NC);
    bscan_k<<<1, 512, 0, stream>>>(btot, bboff, NBK);
    rowoff_k<<<NBK, 512, 0, stream>>>(hist, bboff, hoff, NC);
    fill2<<<NC, 256, 0, stream>>>(srcI, dstI, hoff, binned, E, NC, NBK);
    bucket_scat<<<NBK, 256, 0, stream>>>(binned, bboff, cnt, dinv, cursor, csr_src, N);

    const int gGemm = (N + 63) / 64;
    const int gAgg = (N + 3) / 4;

    // ---- layer 1 ----
    gemm_mfma<true><<<gGemm, 256, 0, stream>>>(x, Wbf1, dinv, gbuf, N);
    agg_csr<<<gAgg, 256, 0, stream>>>(cursor, cnt, csr_src, gbuf, dinv, b1,
                                      (unsigned short*)bufA, N);

    // ---- layer 2 ----
    gemm_mfma<false><<<gGemm, 256, 0, stream>>>(bufA, Wbf2, dinv, gbuf, N);
    agg_csr<<<gAgg, 256, 0, stream>>>(cursor, cnt, csr_src, gbuf, dinv, b2,
                                      (unsigned short*)bufA, N);

    // ---- pool + classifier ----
    pool_kernel<<<PBLK, 256, 0, stream>>>(bufA, partial, N);
    final_kernel<<<1, 128, 0, stream>>>(partial, Wc, bc, (float*)d_out, N, C);
}

// Round 7
// 288.627 us; speedup vs baseline: 2.0631x; 1.0822x over previous
//
#include <hip/hip_runtime.h>
#include <hip/hip_bf16.h>

// GCN: h1 = relu(Agg(x@W1)+b1); h2 = relu(Agg(h1@W2)+b2); out = mean(h2)@Wc + bc
// Agg via CSR gather; g = (X@W)*dinv stored OCP fp8 e4m3 (128B node-major rows).
// r5: agg addressing = 32-bit unsigned byte offsets vs wave-uniform SGPR base:
// gather offB=(src<<7)|(lane<<1), idx=jb+4k. agg 64->55us, VALUBusy 45->30%.
// r6 analysis: agg latency-bound on the per-node dependent chain
// (cursor -> idx-load -> gather). Tail tiers (4-edge batches + serial singles)
// cost deg<16 nodes (46%, Poisson-16) 3-6 serial memory round-trips.
// r7: single MASKED 16-wide tail batch -- idx offsets clamped (uniform s_min)
// to the node's last edge, k>=rem contributions zeroed via cndmask
// (decode(0)=0). Every node = exactly ceil(deg/16) rounds (avg 1.5).
// r6: pool was 62us of global-atomic serialization (WRITE=1024KB = 262144
// write-through RMWs on 8 lines); fixed w/ per-block partials, now ~6us.
// r1-r3: plane-sharded L2-resident gather (FETCH 89.6->37MB) is strictly worse
// (32B rows double L2 transactions, longer chain). Node-major 128B rows win.
// r4: fp8 activations: agg WRITE halves, duration flat -> agg not store-bound.
// CSR build atomic-free; ALL build kernels >= 391 blocks (r11: narrow build
// kernels were width-starved, ~270us invisible tail).
// GEMMs: mfma_f32_16x16x32_bf16, LDS-free, W pre-packed to k-block layout.

#define FEAT 128
#define CHUNK 4096      // edges per chunk (391 chunks)
#define MAXBUCK 512     // max node-buckets (N <= 131072); also NC cap
#define ECAP 12288      // LDS edge staging cap in bucket_scat (48 KB of int)
#define PBLK 512        // pool stage-1 blocks

typedef __attribute__((ext_vector_type(8))) short short8;
typedef __attribute__((ext_vector_type(4))) float float4v;
typedef __attribute__((ext_vector_type(2))) float floatx2;

union I4S8 { int4 i; short8 s; };

static __device__ inline unsigned short f2bf(float f) {
    union { __hip_bfloat16 h; unsigned short u; } cv;
    cv.h = __float2bfloat16(f);
    return cv.u;
}

// ---- OCP fp8 e4m3 helpers ----
static __device__ inline floatx2 fp8x2_dec(unsigned int u) {
#if __has_builtin(__builtin_amdgcn_cvt_pk_f32_fp8)
    return __builtin_amdgcn_cvt_pk_f32_fp8((int)u, false);
#else
    floatx2 r;
    unsigned int b0 = u & 0xFFu, b1 = (u >> 8) & 0xFFu;
    r.x = __uint_as_float(((b0 & 0x80u) << 24) | ((b0 & 0x7Fu) << 20)) * 0x1p+120f;
    r.y = __uint_as_float(((b1 & 0x80u) << 24) | ((b1 & 0x7Fu) << 20)) * 0x1p+120f;
    return r;
#endif
}

static __device__ inline floatx2 fp8x2_dec_hi(unsigned int u) {
#if __has_builtin(__builtin_amdgcn_cvt_pk_f32_fp8)
    return __builtin_amdgcn_cvt_pk_f32_fp8((int)u, true);
#else
    return fp8x2_dec(u >> 16);
#endif
}

// pack two floats -> two fp8 e4m3 bytes (low word)
static __device__ inline unsigned short fp8x2_enc(float x, float y) {
#if __has_builtin(__builtin_amdgcn_cvt_pk_fp8_f32)
    return (unsigned short)(__builtin_amdgcn_cvt_pk_fp8_f32(x, y, 0, false) & 0xFFFF);
#else
    auto enc1 = [](float f) -> unsigned int {
        unsigned int u = __float_as_uint(f);
        unsigned int s = (u >> 24) & 0x80u;
        float a = fabsf(f);
        a = fminf(a, 448.0f);
        unsigned int code;
        if (a < 0.015625f) {
            code = (unsigned int)(int)rintf(a * 512.0f);
        } else {
            unsigned int au = __float_as_uint(a);
            unsigned int r = au + 0x0007FFFFu + ((au >> 20) & 1u);
            unsigned int e = (r >> 23) - 120u;
            unsigned int m = (r >> 20) & 7u;
            code = (e << 3) | m;
            if (code > 0x7Eu) code = 0x7Eu;
        }
        return code | s;
    };
    return (unsigned short)(enc1(x) | (enc1(y) << 8));
#endif
}

static __device__ inline unsigned char fp8enc(float f) {
#if __has_builtin(__builtin_amdgcn_cvt_pk_fp8_f32)
    return (unsigned char)(__builtin_amdgcn_cvt_pk_fp8_f32(f, 0.0f, 0, false) & 0xFF);
#else
    return (unsigned char)(fp8x2_enc(f, 0.0f) & 0xFF);
#endif
}

// ---- build phase 1: per-chunk histogram over node buckets (dst>>8) ----
__global__ __launch_bounds__(256) void hist2(const int* __restrict__ dst,
                                             int* __restrict__ hist,
                                             int nE, int NC, int nbuck) {
    __shared__ int h[MAXBUCK];
    int c = blockIdx.x, t = threadIdx.x;
    for (int i = t; i < nbuck; i += 256) h[i] = 0;
    __syncthreads();
    int beg = c * CHUNK, end = min(nE, beg + CHUNK);
    for (int e = beg + t; e < end; e += 256)
        atomicAdd(&h[dst[e] >> 8], 1);
    __syncthreads();
    for (int i = t; i < nbuck; i += 256) hist[i * NC + c] = h[i];
}

// ---- phase 2a: per-bucket totals (wide: one block per bucket) ----
__global__ __launch_bounds__(256) void rowsum_k(const int* __restrict__ hist,
                                                int* __restrict__ btot, int NC) {
    __shared__ int red[256];
    int b = blockIdx.x, t = threadIdx.x;
    int s = 0;
    for (int c = t; c < NC; c += 256) s += hist[b * NC + c];
    red[t] = s;
    __syncthreads();
    for (int o = 128; o > 0; o >>= 1) {
        if (t < o) red[t] += red[t + o];
        __syncthreads();
    }
    if (t == 0) btot[b] = red[0];
}

// ---- phase 2b: exclusive scan of bucket totals (nbuck <= 512) ----
__global__ __launch_bounds__(512) void bscan_k(const int* __restrict__ btot,
                                               int* __restrict__ bboff, int nbuck) {
    __shared__ int sc[512];
    int t = threadIdx.x;
    int v = (t < nbuck) ? btot[t] : 0;
    sc[t] = v;
    __syncthreads();
    for (int o = 1; o < 512; o <<= 1) {
        int add = (t >= o) ? sc[t - o] : 0;
        __syncthreads();
        sc[t] += add;
        __syncthreads();
    }
    if (t < nbuck) {
        bboff[t] = sc[t] - v;
        if (t == nbuck - 1) bboff[nbuck] = sc[t];
    }
}

// ---- phase 2c: per-(bucket,chunk) offsets (wide: block-parallel scan, NC<=512) ----
__global__ __launch_bounds__(512) void rowoff_k(const int* __restrict__ hist,
                                                const int* __restrict__ bboff,
                                                int* __restrict__ hoff, int NC) {
    __shared__ int sc[512];
    int b = blockIdx.x, t = threadIdx.x;
    int v = (t < NC) ? hist[b * NC + t] : 0;
    sc[t] = v;
    __syncthreads();
    for (int o = 1; o < 512; o <<= 1) {
        int add = (t >= o) ? sc[t - o] : 0;
        __syncthreads();
        sc[t] += add;
        __syncthreads();
    }
    if (t < NC) hoff[b * NC + t] = bboff[b] + sc[t] - v;
}

// ---- phase 3: pack (src<<8|dloc) bucket-grouped; LDS cursors ----
__global__ __launch_bounds__(256) void fill2(const int* __restrict__ src,
                                             const int* __restrict__ dst,
                                             const int* __restrict__ off,
                                             int* __restrict__ binned,
                                             int nE, int NC, int nbuck) {
    __shared__ int cur[MAXBUCK];
    int c = blockIdx.x, t = threadIdx.x;
    for (int i = t; i < nbuck; i += 256) cur[i] = off[i * NC + c];
    __syncthreads();
    int beg = c * CHUNK, end = min(nE, beg + CHUNK);
    for (int e = beg + t; e < end; e += 256) {
        int d = dst[e];
        int pos = atomicAdd(&cur[d >> 8], 1);
        binned[pos] = (src[e] << 8) | (d & 255);
    }
}

// ---- phase 4: per-bucket count + dinv + cursor + csr scatter (all LDS) ----
__global__ __launch_bounds__(256) void bucket_scat(const int* __restrict__ binned,
                                                   const int* __restrict__ bboff,
                                                   int* __restrict__ cnt,
                                                   float* __restrict__ dinv,
                                                   int* __restrict__ cursor,
                                                   int* __restrict__ csr_src, int n) {
    __shared__ int se[ECAP];
    __shared__ int lcnt[256];
    __shared__ int lcur[256];
    __shared__ int ssc[256];
    int b = blockIdx.x, t = threadIdx.x;
    int node0 = b << 8;
    int nloc = min(256, n - node0);
    int ebeg = bboff[b], eend = bboff[b + 1];
    int ne = eend - ebeg;
    lcnt[t] = 0;
    __syncthreads();
    bool staged = (ne <= ECAP);
    if (staged) {
        for (int i = t; i < ne; i += 256) {
            int e = binned[ebeg + i];
            se[i] = e;
            atomicAdd(&lcnt[e & 255], 1);
        }
    } else {
        for (int i = t; i < ne; i += 256)
            atomicAdd(&lcnt[binned[ebeg + i] & 255], 1);
    }
    __syncthreads();
    int myc = (t < nloc) ? lcnt[t] : 0;
    ssc[t] = myc;
    __syncthreads();
    for (int o = 1; o < 256; o <<= 1) {
        int add = (t >= o) ? ssc[t - o] : 0;
        __syncthreads();
        ssc[t] += add;
        __syncthreads();
    }
    int excl = ssc[t] - myc;
    if (t < nloc) {
        cnt[node0 + t] = myc;
        dinv[node0 + t] = rsqrtf((float)(myc + 1));
        cursor[node0 + t] = ebeg + excl;   // cursor = start of node's list
        lcur[t] = excl;
    }
    __syncthreads();
    if (staged) {
        for (int i = t; i < ne; i += 256) {
            int e = se[i];
            int pos = atomicAdd(&lcur[e & 255], 1);
            csr_src[ebeg + pos] = ((unsigned int)e) >> 8;
        }
    } else {
        for (int i = t; i < ne; i += 256) {
            int e = binned[ebeg + i];
            int pos = atomicAdd(&lcur[e & 255], 1);
            csr_src[ebeg + pos] = ((unsigned int)e) >> 8;
        }
    }
}

// ---- W pre-pack (both layers) ----
__global__ __launch_bounds__(256) void wprep2(const float* __restrict__ W1,
                                              const float* __restrict__ W2,
                                              unsigned short* __restrict__ Wbf1,
                                              unsigned short* __restrict__ Wbf2) {
    int tid = blockIdx.x * 256 + threadIdx.x;   // 32768 threads
    const float* W = (tid < 16384) ? W1 : W2;
    unsigned short* O = (tid < 16384) ? Wbf1 : Wbf2;
    int id = tid & 16383;
    int chunk = id >> 3, j = id & 7;
    int kb = chunk >> 7, nn = chunk & 127;
    O[id] = f2bf(W[(kb * 8 + j) * FEAT + nn]);
}

// ---- MFMA GEMM: gout[N][128](fp8) = bf16(X) @ Wbf * dinv[row] ----
// AFP32=true: X is fp32 rows. AFP32=false: X is fp8 e4m3 rows (exact->bf16).
template <bool AFP32>
__global__ __launch_bounds__(256) void gemm_mfma(const void* __restrict__ Xv,
                                                 const unsigned short* __restrict__ Wbf,
                                                 const float* __restrict__ dinv,
                                                 unsigned char* __restrict__ gout,
                                                 int n) {
    int wave = threadIdx.x >> 6, lane = threadIdx.x & 63;
    int m0 = blockIdx.x * 64 + wave * 16;
    if (m0 >= n) return;
    int col = lane & 15, quad = lane >> 4;
    int mc = min(m0 + col, n - 1);

    short8 afr[4];
    if (AFP32) {
        const float* X = (const float*)Xv;
        const float* xr = X + (size_t)mc * FEAT + quad * 8;
#pragma unroll
        for (int ks = 0; ks < 4; ks++) {
            float4 lo = *(const float4*)(xr + ks * 32);
            float4 hi = *(const float4*)(xr + ks * 32 + 4);
            short8 a;
            a[0] = (short)f2bf(lo.x); a[1] = (short)f2bf(lo.y);
            a[2] = (short)f2bf(lo.z); a[3] = (short)f2bf(lo.w);
            a[4] = (short)f2bf(hi.x); a[5] = (short)f2bf(hi.y);
            a[6] = (short)f2bf(hi.z); a[7] = (short)f2bf(hi.w);
            afr[ks] = a;
        }
    } else {
        const unsigned char* X8 = (const unsigned char*)Xv;
        const unsigned char* xr = X8 + (size_t)mc * FEAT + quad * 8;
#pragma unroll
        for (int ks = 0; ks < 4; ks++) {
            uint2 u2 = *(const uint2*)(xr + ks * 32);
            floatx2 p0 = fp8x2_dec(u2.x);
            floatx2 p1 = fp8x2_dec_hi(u2.x);
            floatx2 p2 = fp8x2_dec(u2.y);
            floatx2 p3 = fp8x2_dec_hi(u2.y);
            short8 a;
            a[0] = (short)f2bf(p0.x); a[1] = (short)f2bf(p0.y);
            a[2] = (short)f2bf(p1.x); a[3] = (short)f2bf(p1.y);
            a[4] = (short)f2bf(p2.x); a[5] = (short)f2bf(p2.y);
            a[6] = (short)f2bf(p3.x); a[7] = (short)f2bf(p3.y);
            afr[ks] = a;
        }
    }

    float dvr[4];
#pragma unroll
    for (int r = 0; r < 4; r++)
        dvr[r] = dinv[min(m0 + quad * 4 + r, n - 1)];

    const int4* Wb = (const int4*)Wbf;
#pragma unroll
    for (int nt = 0; nt < 8; nt++) {
        float4v acc = {0.f, 0.f, 0.f, 0.f};
#pragma unroll
        for (int ks = 0; ks < 4; ks++) {
            int kb = ks * 4 + quad;
            I4S8 u; u.i = Wb[kb * FEAT + nt * 16 + col];
            acc = __builtin_amdgcn_mfma_f32_16x16x32_bf16(afr[ks], u.s, acc, 0, 0, 0);
        }
#pragma unroll
        for (int r = 0; r < 4; r++) {
            int row = m0 + quad * 4 + r;
            if (row < n)
                gout[(size_t)row * FEAT + nt * 16 + col] = fp8enc(acc[r] * dvr[r]);
        }
    }
}

// ---- gather-sum core for one node (fp8 rows, 2 feats/lane) ----
// 32-bit byte offsets vs wave-uniform bases (r5). r7: full 16-batches then ONE
// masked 16-batch tail: idx offsets clamped to last edge (uniform min), k>=rem
// contributions zeroed via cndmask (decode(0)=0). Rounds = ceil(deg/16).
static __device__ inline void gather_node(const unsigned char* __restrict__ csrB,
                                          const unsigned char* __restrict__ gb,
                                          int beg, int end, unsigned node,
                                          unsigned lane2, float& sx, float& sy) {
    floatx2 a0 = fp8x2_dec(*(const unsigned short*)(gb + ((node << 7) | lane2)));
    floatx2 a1 = {0.f, 0.f}, a2 = {0.f, 0.f}, a3 = {0.f, 0.f};
    int j = beg;
    // full 16-edge batches (no masking)
    for (; j + 16 <= end; j += 16) {
        unsigned jb = (unsigned)j << 2;
        unsigned sIdx[16];
#pragma unroll
        for (int k = 0; k < 16; k++)
            sIdx[k] = *(const unsigned*)(csrB + (jb + 4u * (unsigned)k));
        unsigned short uu[16];
#pragma unroll
        for (int k = 0; k < 16; k++)
            uu[k] = *(const unsigned short*)(gb + ((sIdx[k] << 7) | lane2));
#pragma unroll
        for (int k = 0; k < 16; k += 4) {
            a0 += fp8x2_dec(uu[k]);
            a1 += fp8x2_dec(uu[k + 1]);
            a2 += fp8x2_dec(uu[k + 2]);
            a3 += fp8x2_dec(uu[k + 3]);
        }
    }
    // single masked tail batch (rem in 1..15), one round-trip pair
    if (j < end) {
        int rem = end - j;                        // wave-uniform
        unsigned jb = (unsigned)j << 2;
        unsigned jend4 = ((unsigned)(end - 1)) << 2;
        unsigned sIdx[16];
#pragma unroll
        for (int k = 0; k < 16; k++) {
            unsigned o = jb + 4u * (unsigned)k;
            o = (o > jend4) ? jend4 : o;          // clamp: stays in node's list
            sIdx[k] = *(const unsigned*)(csrB + o);
        }
        unsigned short uu[16];
#pragma unroll
        for (int k = 0; k < 16; k++)
            uu[k] = *(const unsigned short*)(gb + ((sIdx[k] << 7) | lane2));
#pragma unroll
        for (int k = 0; k < 16; k += 4) {
            unsigned v0 = (k + 0 < rem) ? (unsigned)uu[k + 0] : 0u;
            unsigned v1 = (k + 1 < rem) ? (unsigned)uu[k + 1] : 0u;
            unsigned v2 = (k + 2 < rem) ? (unsigned)uu[k + 2] : 0u;
            unsigned v3 = (k + 3 < rem) ? (unsigned)uu[k + 3] : 0u;
            a0 += fp8x2_dec(v0);
            a1 += fp8x2_dec(v1);
            a2 += fp8x2_dec(v2);
            a3 += fp8x2_dec(v3);
        }
    }
    floatx2 a = (a0 + a1) + (a2 + a3);
    sx = a.x;
    sy = a.y;
}

// ---- agg: CSR gather + bias + relu -> fp8 rows (1 node per wave) ----
__global__ __launch_bounds__(256) void agg_csr(const int* __restrict__ cursor,
                                               const int* __restrict__ cnt,
                                               const int* __restrict__ csr_src,
                                               const unsigned char* __restrict__ gbuf,
                                               const float* __restrict__ dinv,
                                               const float* __restrict__ bias,
                                               unsigned short* __restrict__ outb,
                                               int n) {
    int node = blockIdx.x * 4 + (threadIdx.x >> 6);
    if (node >= n) return;
    unsigned lane = threadIdx.x & 63;
    unsigned lane2 = lane << 1;
    int beg = cursor[node];
    int end = beg + cnt[node];
    float sx, sy;
    gather_node((const unsigned char*)csr_src, gbuf, beg, end,
                (unsigned)node, lane2, sx, sy);
    float dv = dinv[node];
    float2 bv = ((const float2*)bias)[lane];
    float rx = fmaxf(sx * dv + bv.x, 0.0f);
    float ry = fmaxf(sy * dv + bv.y, 0.0f);
    outb[(((unsigned)node) << 6) | lane] = fp8x2_enc(rx, ry);
}

// ---- mean pool stage 1: per-block partial sums, NO global atomics ----
// thread: fg = t&15 (8 feats via uint2), rg = t>>4 (row in block group).
// wave = 4 consecutive rows x 128B = 512B contiguous per load instruction.
__global__ __launch_bounds__(256) void pool_kernel(const unsigned char* __restrict__ a,
                                                   float* __restrict__ partial, int n) {
    __shared__ float red[16][132];   // +4 pad
    int t = threadIdx.x, b = blockIdx.x;
    int fg = t & 15;
    int rg = t >> 4;
    unsigned fb = (unsigned)fg << 3;             // feature byte offset
    floatx2 s01 = {0.f, 0.f}, s23 = {0.f, 0.f}, s45 = {0.f, 0.f}, s67 = {0.f, 0.f};
    for (int i = (b << 4) | rg; i < n; i += PBLK * 16) {
        uint2 u2 = *(const uint2*)(a + (((unsigned)i << 7) | fb));
        s01 += fp8x2_dec(u2.x);
        s23 += fp8x2_dec_hi(u2.x);
        s45 += fp8x2_dec(u2.y);
        s67 += fp8x2_dec_hi(u2.y);
    }
    red[rg][fb + 0] = s01.x; red[rg][fb + 1] = s01.y;
    red[rg][fb + 2] = s23.x; red[rg][fb + 3] = s23.y;
    red[rg][fb + 4] = s45.x; red[rg][fb + 5] = s45.y;
    red[rg][fb + 6] = s67.x; red[rg][fb + 7] = s67.y;
    __syncthreads();
    if (t < FEAT) {
        float s = 0.0f;
#pragma unroll
        for (int k = 0; k < 16; k++) s += red[k][t];
        partial[b * FEAT + t] = s;
    }
}

// ---- final: reduce partials; out[c] = (pooled/N) . Wc[:,c] + bc[c] ----
__global__ __launch_bounds__(128) void final_kernel(const float* __restrict__ partial,
                                                    const float* __restrict__ Wc,
                                                    const float* __restrict__ bc,
                                                    float* __restrict__ out,
                                                    int n, int C) {
    __shared__ float p[FEAT];
    int t = threadIdx.x;
    float s = 0.0f;
    for (int b = 0; b < PBLK; b++) s += partial[b * FEAT + t];
    p[t] = s * (1.0f / (float)n);
    __syncthreads();
    if (t < C) {
        float acc = bc[t];
        for (int h = 0; h < FEAT; h++)
            acc += p[h] * Wc[h * C + t];
        out[t] = acc;
    }
}

extern "C" void kernel_launch(void* const* d_in, const int* in_sizes, int n_in,
                              void* d_out, int out_size, void* d_ws, size_t ws_size,
                              hipStream_t stream) {
    const float* x  = (const float*)d_in[0];
    const int*   ei = (const int*)d_in[1];
    const float* W1 = (const float*)d_in[2];
    const float* b1 = (const float*)d_in[3];
    const float* W2 = (const float*)d_in[4];
    const float* b2 = (const float*)d_in[5];
    const float* Wc = (const float*)d_in[6];
    const float* bc = (const float*)d_in[7];

    const int N = in_sizes[0] / FEAT;        // 100000
    const int E = in_sizes[1] / 2;           // 1600000
    const int C = out_size;                  // 32
    const int* srcI = ei;
    const int* dstI = ei + E;
    const int NC = (E + CHUNK - 1) / CHUNK;  // edge chunks (391, <= 512)
    const int NBK = (N + 255) >> 8;          // node buckets (391, <= MAXBUCK)

    // workspace carve (256B aligned)
    auto align256 = [](size_t v) { return (v + 255) & ~(size_t)255; };
    char* w = (char*)d_ws;
    int*            cnt     = (int*)w;            w += align256((size_t)N * 4);
    float*          dinv    = (float*)w;          w += align256((size_t)N * 4);
    int*            cursor  = (int*)w;            w += align256((size_t)N * 4);
    int*            csr_src = (int*)w;            w += align256((size_t)E * 4);
    int*            binned  = (int*)w;            w += align256((size_t)E * 4);
    int*            hist    = (int*)w;            w += align256((size_t)NBK * NC * 4);
    int*            hoff    = (int*)w;            w += align256((size_t)NBK * NC * 4);
    int*            btot    = (int*)w;            w += align256((size_t)NBK * 4);
    int*            bboff   = (int*)w;            w += align256((size_t)(NBK + 1) * 4);
    unsigned short* Wbf1    = (unsigned short*)w; w += align256((size_t)FEAT * FEAT * 2);
    unsigned short* Wbf2    = (unsigned short*)w; w += align256((size_t)FEAT * FEAT * 2);
    unsigned char*  gbuf    = (unsigned char*)w;  w += align256((size_t)N * FEAT);
    unsigned char*  bufA    = (unsigned char*)w;  w += align256((size_t)N * FEAT);
    float*          partial = (float*)w;          w += align256((size_t)PBLK * FEAT * 4);

    // W pre-pack (both layers)
    wprep2<<<128, 256, 0, stream>>>(W1, W2, Wbf1, Wbf2);

    // ---- atomic-free CSR build (all kernels >= 391 blocks except bscan) ----
    hist2<<<NC, 256, 0, stream>>>(dstI, hist, E, NC, NBK);
    rowsum_k<<<NBK, 256, 0, stream>>>(hist, btot, NC);
    bscan_k<<<1, 512, 0, stream>>>(btot, bboff, NBK);
    rowoff_k<<<NBK, 512, 0, stream>>>(hist, bboff, hoff, NC);
    fill2<<<NC, 256, 0, stream>>>(srcI, dstI, hoff, binned, E, NC, NBK);
    bucket_scat<<<NBK, 256, 0, stream>>>(binned, bboff, cnt, dinv, cursor, csr_src, N);

    const int gGemm = (N + 63) / 64;
    const int gAgg = (N + 3) / 4;

    // ---- layer 1 ----
    gemm_mfma<true><<<gGemm, 256, 0, stream>>>(x, Wbf1, dinv, gbuf, N);
    agg_csr<<<gAgg, 256, 0, stream>>>(cursor, cnt, csr_src, gbuf, dinv, b1,
                                      (unsigned short*)bufA, N);

    // ---- layer 2 ----
    gemm_mfma<false><<<gGemm, 256, 0, stream>>>(bufA, Wbf2, dinv, gbuf, N);
    agg_csr<<<gAgg, 256, 0, stream>>>(cursor, cnt, csr_src, gbuf, dinv, b2,
                                      (unsigned short*)bufA, N);

    // ---- pool + classifier ----
    pool_kernel<<<PBLK, 256, 0, stream>>>(bufA, partial, N);
    final_kernel<<<1, 128, 0, stream>>>(partial, Wc, bc, (float*)d_out, N, C);
}

// Round 9
// 279.345 us; speedup vs baseline: 2.1316x; 1.0332x over previous
//
#include <hip/hip_runtime.h>
#include <hip/hip_bf16.h>

// GCN: h1 = relu(Agg(x@W1)+b1); h2 = relu(Agg(h1@W2)+b2); out = mean(h2)@Wc + bc
// Agg via CSR gather; g = (X@W)*dinv stored OCP fp8 e4m3 (128B node-major rows,
// plus ONE ZERO ROW at index N for CSR padding).
// r8 (inline-asm s_load_dwordx8 idx fetch) ABORTED on HW -> rolled back; same
// VALU-diet goal achieved in plain HIP:
//   r9a: CSR PADDED to 16-edge multiples per node; pad entries = (N<<7) ->
//        zero row (fp8 0x00 = 0.0 exact). NO tail masking in agg at all.
//        Deterministic layout: bucket b base = (bboff[b]+3856*b+15)&~15.
//   r9b: idx stream via 4 x int4 loads per batch (16B-aligned by layout).
//   r9c: scalar loop bounds via readfirstlane (no asm); csr entries stored
//        PRE-SHIFTED (src<<7) -> gather addr = v_or(idx,lane2), 1 VALU/edge.
// r7: masked tail -> rounds=ceil(deg/16); agg 55->48us, VALUBusy 30->56%.
// r6: pool was 62us of global-atomic serialization; per-block partials ~6us.
// r5: 32-bit byte-offset addressing (agg 64->55us, VALUBusy 45->30%).
// r4: fp8 activations (agg WRITE halves; duration flat -> not store-bound).
// r1-r3: plane-sharded L2-resident gather strictly worse (2x L2 transactions).
// CSR build atomic-free; ALL build kernels >= 391 blocks (r11: narrow build
// kernels were width-starved, ~270us invisible tail).
// GEMMs: mfma_f32_16x16x32_bf16, LDS-free, W pre-packed to k-block layout.

#define FEAT 128
#define CHUNK 4096      // edges per chunk (391 chunks)
#define MAXBUCK 512     // max node-buckets (N <= 131072); also NC cap
#define ECAP 12288      // LDS edge staging cap in bucket_scat (48 KB of int)
#define PBLK 512        // pool stage-1 blocks
#define BPAD 3856       // per-bucket padded-layout slack (15*256 + align)

typedef __attribute__((ext_vector_type(8))) short short8;
typedef __attribute__((ext_vector_type(4))) float float4v;
typedef __attribute__((ext_vector_type(2))) float floatx2;

union I4S8 { int4 i; short8 s; };

static __device__ inline unsigned short f2bf(float f) {
    union { __hip_bfloat16 h; unsigned short u; } cv;
    cv.h = __float2bfloat16(f);
    return cv.u;
}

// ---- OCP fp8 e4m3 helpers ----
static __device__ inline floatx2 fp8x2_dec(unsigned int u) {
#if __has_builtin(__builtin_amdgcn_cvt_pk_f32_fp8)
    return __builtin_amdgcn_cvt_pk_f32_fp8((int)u, false);
#else
    floatx2 r;
    unsigned int b0 = u & 0xFFu, b1 = (u >> 8) & 0xFFu;
    r.x = __uint_as_float(((b0 & 0x80u) << 24) | ((b0 & 0x7Fu) << 20)) * 0x1p+120f;
    r.y = __uint_as_float(((b1 & 0x80u) << 24) | ((b1 & 0x7Fu) << 20)) * 0x1p+120f;
    return r;
#endif
}

static __device__ inline floatx2 fp8x2_dec_hi(unsigned int u) {
#if __has_builtin(__builtin_amdgcn_cvt_pk_f32_fp8)
    return __builtin_amdgcn_cvt_pk_f32_fp8((int)u, true);
#else
    return fp8x2_dec(u >> 16);
#endif
}

// pack two floats -> two fp8 e4m3 bytes (low word)
static __device__ inline unsigned short fp8x2_enc(float x, float y) {
#if __has_builtin(__builtin_amdgcn_cvt_pk_fp8_f32)
    return (unsigned short)(__builtin_amdgcn_cvt_pk_fp8_f32(x, y, 0, false) & 0xFFFF);
#else
    auto enc1 = [](float f) -> unsigned int {
        unsigned int u = __float_as_uint(f);
        unsigned int s = (u >> 24) & 0x80u;
        float a = fabsf(f);
        a = fminf(a, 448.0f);
        unsigned int code;
        if (a < 0.015625f) {
            code = (unsigned int)(int)rintf(a * 512.0f);
        } else {
            unsigned int au = __float_as_uint(a);
            unsigned int r = au + 0x0007FFFFu + ((au >> 20) & 1u);
            unsigned int e = (r >> 23) - 120u;
            unsigned int m = (r >> 20) & 7u;
            code = (e << 3) | m;
            if (code > 0x7Eu) code = 0x7Eu;
        }
        return code | s;
    };
    return (unsigned short)(enc1(x) | (enc1(y) << 8));
#endif
}

static __device__ inline unsigned char fp8enc(float f) {
#if __has_builtin(__builtin_amdgcn_cvt_pk_fp8_f32)
    return (unsigned char)(__builtin_amdgcn_cvt_pk_fp8_f32(f, 0.0f, 0, false) & 0xFF);
#else
    return (unsigned char)(fp8x2_enc(f, 0.0f) & 0xFF);
#endif
}

// ---- build phase 1: per-chunk histogram over node buckets (dst>>8) ----
__global__ __launch_bounds__(256) void hist2(const int* __restrict__ dst,
                                             int* __restrict__ hist,
                                             int nE, int NC, int nbuck) {
    __shared__ int h[MAXBUCK];
    int c = blockIdx.x, t = threadIdx.x;
    for (int i = t; i < nbuck; i += 256) h[i] = 0;
    __syncthreads();
    int beg = c * CHUNK, end = min(nE, beg + CHUNK);
    for (int e = beg + t; e < end; e += 256)
        atomicAdd(&h[dst[e] >> 8], 1);
    __syncthreads();
    for (int i = t; i < nbuck; i += 256) hist[i * NC + c] = h[i];
}

// ---- phase 2a: per-bucket totals (wide: one block per bucket) ----
__global__ __launch_bounds__(256) void rowsum_k(const int* __restrict__ hist,
                                                int* __restrict__ btot, int NC) {
    __shared__ int red[256];
    int b = blockIdx.x, t = threadIdx.x;
    int s = 0;
    for (int c = t; c < NC; c += 256) s += hist[b * NC + c];
    red[t] = s;
    __syncthreads();
    for (int o = 128; o > 0; o >>= 1) {
        if (t < o) red[t] += red[t + o];
        __syncthreads();
    }
    if (t == 0) btot[b] = red[0];
}

// ---- phase 2b: exclusive scan of bucket totals (nbuck <= 512) ----
__global__ __launch_bounds__(512) void bscan_k(const int* __restrict__ btot,
                                               int* __restrict__ bboff, int nbuck) {
    __shared__ int sc[512];
    int t = threadIdx.x;
    int v = (t < nbuck) ? btot[t] : 0;
    sc[t] = v;
    __syncthreads();
    for (int o = 1; o < 512; o <<= 1) {
        int add = (t >= o) ? sc[t - o] : 0;
        __syncthreads();
        sc[t] += add;
        __syncthreads();
    }
    if (t < nbuck) {
        bboff[t] = sc[t] - v;
        if (t == nbuck - 1) bboff[nbuck] = sc[t];
    }
}

// ---- phase 2c: per-(bucket,chunk) offsets (wide: block-parallel scan, NC<=512) ----
__global__ __launch_bounds__(512) void rowoff_k(const int* __restrict__ hist,
                                                const int* __restrict__ bboff,
                                                int* __restrict__ hoff, int NC) {
    __shared__ int sc[512];
    int b = blockIdx.x, t = threadIdx.x;
    int v = (t < NC) ? hist[b * NC + t] : 0;
    sc[t] = v;
    __syncthreads();
    for (int o = 1; o < 512; o <<= 1) {
        int add = (t >= o) ? sc[t - o] : 0;
        __syncthreads();
        sc[t] += add;
        __syncthreads();
    }
    if (t < NC) hoff[b * NC + t] = bboff[b] + sc[t] - v;
}

// ---- phase 3: pack (src<<8|dloc) bucket-grouped; LDS cursors ----
__global__ __launch_bounds__(256) void fill2(const int* __restrict__ src,
                                             const int* __restrict__ dst,
                                             const int* __restrict__ off,
                                             int* __restrict__ binned,
                                             int nE, int NC, int nbuck) {
    __shared__ int cur[MAXBUCK];
    int c = blockIdx.x, t = threadIdx.x;
    for (int i = t; i < nbuck; i += 256) cur[i] = off[i * NC + c];
    __syncthreads();
    int beg = c * CHUNK, end = min(nE, beg + CHUNK);
    for (int e = beg + t; e < end; e += 256) {
        int d = dst[e];
        int pos = atomicAdd(&cur[d >> 8], 1);
        binned[pos] = (src[e] << 8) | (d & 255);
    }
}

// ---- phase 4: per-bucket count + dinv + cursor + PADDED csr scatter ----
// Padded layout: bucket b base = (bboff[b] + BPAD*b + 15) & ~15 (16-aligned,
// regions provably disjoint). Each node's list padded to multiple of 16 with
// entries = (n<<7) -> gbuf zero row. cnt[] stores the PADDED count (loop
// bound); dinv uses the real degree. csr entries PRE-SHIFTED (src<<7).
__global__ __launch_bounds__(256) void bucket_scat(const int* __restrict__ binned,
                                                   const int* __restrict__ bboff,
                                                   int* __restrict__ cnt,
                                                   float* __restrict__ dinv,
                                                   int* __restrict__ cursor,
                                                   int* __restrict__ csr_src, int n) {
    __shared__ int se[ECAP];
    __shared__ int lcnt[256];
    __shared__ int lcur[256];
    __shared__ int ssc[256];
    int b = blockIdx.x, t = threadIdx.x;
    int node0 = b << 8;
    int nloc = min(256, n - node0);
    int ebeg = bboff[b], eend = bboff[b + 1];
    int ne = eend - ebeg;
    int pbase = (ebeg + b * BPAD + 15) & ~15;   // 16-aligned padded bucket base
    int zOff = n << 7;                          // zero-row byte offset
    lcnt[t] = 0;
    __syncthreads();
    bool staged = (ne <= ECAP);
    if (staged) {
        for (int i = t; i < ne; i += 256) {
            int e = binned[ebeg + i];
            se[i] = e;
            atomicAdd(&lcnt[e & 255], 1);
        }
    } else {
        for (int i = t; i < ne; i += 256)
            atomicAdd(&lcnt[binned[ebeg + i] & 255], 1);
    }
    __syncthreads();
    int myc = (t < nloc) ? lcnt[t] : 0;
    int mycp = (myc + 15) & ~15;                // padded degree
    ssc[t] = mycp;
    __syncthreads();
    for (int o = 1; o < 256; o <<= 1) {
        int add = (t >= o) ? ssc[t - o] : 0;
        __syncthreads();
        ssc[t] += add;
        __syncthreads();
    }
    int exclp = ssc[t] - mycp;
    if (t < nloc) {
        cnt[node0 + t] = mycp;                  // PADDED count for agg loop
        dinv[node0 + t] = rsqrtf((float)(myc + 1));
        cursor[node0 + t] = pbase + exclp;      // start of node's padded list
        lcur[t] = exclp;
    }
    __syncthreads();
    if (staged) {
        for (int i = t; i < ne; i += 256) {
            int e = se[i];
            int pos = atomicAdd(&lcur[e & 255], 1);
            csr_src[pbase + pos] = (int)(((unsigned int)e >> 8) << 7);
        }
    } else {
        for (int i = t; i < ne; i += 256) {
            int e = binned[ebeg + i];
            int pos = atomicAdd(&lcur[e & 255], 1);
            csr_src[pbase + pos] = (int)(((unsigned int)e >> 8) << 7);
        }
    }
    // pad fill (disjoint from scatter ranges; no sync needed)
    if (t < nloc) {
        for (int i = exclp + myc; i < exclp + mycp; i++)
            csr_src[pbase + i] = zOff;
    }
}

// ---- W pre-pack (both layers) + gbuf zero-row init ----
__global__ __launch_bounds__(256) void wprep2(const float* __restrict__ W1,
                                              const float* __restrict__ W2,
                                              unsigned short* __restrict__ Wbf1,
                                              unsigned short* __restrict__ Wbf2,
                                              unsigned char* __restrict__ gbuf,
                                              int n) {
    int tid = blockIdx.x * 256 + threadIdx.x;   // 32768 threads
    if (tid < 32)
        ((unsigned int*)(gbuf + (size_t)n * FEAT))[tid] = 0u;  // zero row N
    const float* W = (tid < 16384) ? W1 : W2;
    unsigned short* O = (tid < 16384) ? Wbf1 : Wbf2;
    int id = tid & 16383;
    int chunk = id >> 3, j = id & 7;
    int kb = chunk >> 7, nn = chunk & 127;
    O[id] = f2bf(W[(kb * 8 + j) * FEAT + nn]);
}

// ---- MFMA GEMM: gout[N][128](fp8) = bf16(X) @ Wbf * dinv[row] ----
// AFP32=true: X is fp32 rows. AFP32=false: X is fp8 e4m3 rows (exact->bf16).
template <bool AFP32>
__global__ __launch_bounds__(256) void gemm_mfma(const void* __restrict__ Xv,
                                                 const unsigned short* __restrict__ Wbf,
                                                 const float* __restrict__ dinv,
                                                 unsigned char* __restrict__ gout,
                                                 int n) {
    int wave = threadIdx.x >> 6, lane = threadIdx.x & 63;
    int m0 = blockIdx.x * 64 + wave * 16;
    if (m0 >= n) return;
    int col = lane & 15, quad = lane >> 4;
    int mc = min(m0 + col, n - 1);

    short8 afr[4];
    if (AFP32) {
        const float* X = (const float*)Xv;
        const float* xr = X + (size_t)mc * FEAT + quad * 8;
#pragma unroll
        for (int ks = 0; ks < 4; ks++) {
            float4 lo = *(const float4*)(xr + ks * 32);
            float4 hi = *(const float4*)(xr + ks * 32 + 4);
            short8 a;
            a[0] = (short)f2bf(lo.x); a[1] = (short)f2bf(lo.y);
            a[2] = (short)f2bf(lo.z); a[3] = (short)f2bf(lo.w);
            a[4] = (short)f2bf(hi.x); a[5] = (short)f2bf(hi.y);
            a[6] = (short)f2bf(hi.z); a[7] = (short)f2bf(hi.w);
            afr[ks] = a;
        }
    } else {
        const unsigned char* X8 = (const unsigned char*)Xv;
        const unsigned char* xr = X8 + (size_t)mc * FEAT + quad * 8;
#pragma unroll
        for (int ks = 0; ks < 4; ks++) {
            uint2 u2 = *(const uint2*)(xr + ks * 32);
            floatx2 p0 = fp8x2_dec(u2.x);
            floatx2 p1 = fp8x2_dec_hi(u2.x);
            floatx2 p2 = fp8x2_dec(u2.y);
            floatx2 p3 = fp8x2_dec_hi(u2.y);
            short8 a;
            a[0] = (short)f2bf(p0.x); a[1] = (short)f2bf(p0.y);
            a[2] = (short)f2bf(p1.x); a[3] = (short)f2bf(p1.y);
            a[4] = (short)f2bf(p2.x); a[5] = (short)f2bf(p2.y);
            a[6] = (short)f2bf(p3.x); a[7] = (short)f2bf(p3.y);
            afr[ks] = a;
        }
    }

    float dvr[4];
#pragma unroll
    for (int r = 0; r < 4; r++)
        dvr[r] = dinv[min(m0 + quad * 4 + r, n - 1)];

    const int4* Wb = (const int4*)Wbf;
#pragma unroll
    for (int nt = 0; nt < 8; nt++) {
        float4v acc = {0.f, 0.f, 0.f, 0.f};
#pragma unroll
        for (int ks = 0; ks < 4; ks++) {
            int kb = ks * 4 + quad;
            I4S8 u; u.i = Wb[kb * FEAT + nt * 16 + col];
            acc = __builtin_amdgcn_mfma_f32_16x16x32_bf16(afr[ks], u.s, acc, 0, 0, 0);
        }
#pragma unroll
        for (int r = 0; r < 4; r++) {
            int row = m0 + quad * 4 + r;
            if (row < n)
                gout[(size_t)row * FEAT + nt * 16 + col] = fp8enc(acc[r] * dvr[r]);
        }
    }
}

// ---- agg: padded CSR gather + bias + relu -> fp8 rows (1 node per wave) ----
// cnt[] is padded to x16 -> single unmasked loop, rounds = cnt/16.
// Idx via 4 x int4 loads (16B-aligned by layout); csr entries pre-shifted so
// gather voffset = idx | lane2 (1 VALU). Scalar loop bounds (readfirstlane).
__global__ __launch_bounds__(256) void agg_csr(const int* __restrict__ cursor,
                                               const int* __restrict__ cnt,
                                               const int* __restrict__ csr_src,
                                               const unsigned char* __restrict__ gbuf,
                                               const float* __restrict__ dinv,
                                               const float* __restrict__ bias,
                                               unsigned short* __restrict__ outb,
                                               int n) {
    int node = blockIdx.x * 4 + (threadIdx.x >> 6);
    if (node >= n) return;
    unsigned lane = threadIdx.x & 63;
    unsigned lane2 = lane << 1;
    int begS = __builtin_amdgcn_readfirstlane(cursor[node]);
    int endS = begS + __builtin_amdgcn_readfirstlane(cnt[node]);
    const unsigned char* csrB = (const unsigned char*)csr_src;

    floatx2 a0 = fp8x2_dec(*(const unsigned short*)(gbuf + ((((unsigned)node) << 7) | lane2)));
    floatx2 a1 = {0.f, 0.f}, a2 = {0.f, 0.f}, a3 = {0.f, 0.f};

    for (int j = begS; j < endS; j += 16) {
        const unsigned char* p = csrB + ((size_t)(unsigned)j << 2);
        int4 w0 = *(const int4*)(p);
        int4 w1 = *(const int4*)(p + 16);
        int4 w2 = *(const int4*)(p + 32);
        int4 w3 = *(const int4*)(p + 48);
        unsigned short uu[16];
        uu[0]  = *(const unsigned short*)(gbuf + ((unsigned)w0.x | lane2));
        uu[1]  = *(const unsigned short*)(gbuf + ((unsigned)w0.y | lane2));
        uu[2]  = *(const unsigned short*)(gbuf + ((unsigned)w0.z | lane2));
        uu[3]  = *(const unsigned short*)(gbuf + ((unsigned)w0.w | lane2));
        uu[4]  = *(const unsigned short*)(gbuf + ((unsigned)w1.x | lane2));
        uu[5]  = *(const unsigned short*)(gbuf + ((unsigned)w1.y | lane2));
        uu[6]  = *(const unsigned short*)(gbuf + ((unsigned)w1.z | lane2));
        uu[7]  = *(const unsigned short*)(gbuf + ((unsigned)w1.w | lane2));
        uu[8]  = *(const unsigned short*)(gbuf + ((unsigned)w2.x | lane2));
        uu[9]  = *(const unsigned short*)(gbuf + ((unsigned)w2.y | lane2));
        uu[10] = *(const unsigned short*)(gbuf + ((unsigned)w2.z | lane2));
        uu[11] = *(const unsigned short*)(gbuf + ((unsigned)w2.w | lane2));
        uu[12] = *(const unsigned short*)(gbuf + ((unsigned)w3.x | lane2));
        uu[13] = *(const unsigned short*)(gbuf + ((unsigned)w3.y | lane2));
        uu[14] = *(const unsigned short*)(gbuf + ((unsigned)w3.z | lane2));
        uu[15] = *(const unsigned short*)(gbuf + ((unsigned)w3.w | lane2));
#pragma unroll
        for (int k = 0; k < 16; k += 4) {
            a0 += fp8x2_dec(uu[k]);
            a1 += fp8x2_dec(uu[k + 1]);
            a2 += fp8x2_dec(uu[k + 2]);
            a3 += fp8x2_dec(uu[k + 3]);
        }
    }
    floatx2 a = (a0 + a1) + (a2 + a3);
    float dv = dinv[node];
    float2 bv = ((const float2*)bias)[lane];
    float rx = fmaxf(a.x * dv + bv.x, 0.0f);
    float ry = fmaxf(a.y * dv + bv.y, 0.0f);
    outb[(((unsigned)node) << 6) | lane] = fp8x2_enc(rx, ry);
}

// ---- mean pool stage 1: per-block partial sums, NO global atomics ----
// thread: fg = t&15 (8 feats via uint2), rg = t>>4 (row in block group).
// wave = 4 consecutive rows x 128B = 512B contiguous per load instruction.
__global__ __launch_bounds__(256) void pool_kernel(const unsigned char* __restrict__ a,
                                                   float* __restrict__ partial, int n) {
    __shared__ float red[16][132];   // +4 pad
    int t = threadIdx.x, b = blockIdx.x;
    int fg = t & 15;
    int rg = t >> 4;
    unsigned fb = (unsigned)fg << 3;             // feature byte offset
    floatx2 s01 = {0.f, 0.f}, s23 = {0.f, 0.f}, s45 = {0.f, 0.f}, s67 = {0.f, 0.f};
    for (int i = (b << 4) | rg; i < n; i += PBLK * 16) {
        uint2 u2 = *(const uint2*)(a + (((unsigned)i << 7) | fb));
        s01 += fp8x2_dec(u2.x);
        s23 += fp8x2_dec_hi(u2.x);
        s45 += fp8x2_dec(u2.y);
        s67 += fp8x2_dec_hi(u2.y);
    }
    red[rg][fb + 0] = s01.x; red[rg][fb + 1] = s01.y;
    red[rg][fb + 2] = s23.x; red[rg][fb + 3] = s23.y;
    red[rg][fb + 4] = s45.x; red[rg][fb + 5] = s45.y;
    red[rg][fb + 6] = s67.x; red[rg][fb + 7] = s67.y;
    __syncthreads();
    if (t < FEAT) {
        float s = 0.0f;
#pragma unroll
        for (int k = 0; k < 16; k++) s += red[k][t];
        partial[b * FEAT + t] = s;
    }
}

// ---- final: reduce partials; out[c] = (pooled/N) . Wc[:,c] + bc[c] ----
__global__ __launch_bounds__(128) void final_kernel(const float* __restrict__ partial,
                                                    const float* __restrict__ Wc,
                                                    const float* __restrict__ bc,
                                                    float* __restrict__ out,
                                                    int n, int C) {
    __shared__ float p[FEAT];
    int t = threadIdx.x;
    float s = 0.0f;
    for (int b = 0; b < PBLK; b++) s += partial[b * FEAT + t];
    p[t] = s * (1.0f / (float)n);
    __syncthreads();
    if (t < C) {
        float acc = bc[t];
        for (int h = 0; h < FEAT; h++)
            acc += p[h] * Wc[h * C + t];
        out[t] = acc;
    }
}

extern "C" void kernel_launch(void* const* d_in, const int* in_sizes, int n_in,
                              void* d_out, int out_size, void* d_ws, size_t ws_size,
                              hipStream_t stream) {
    const float* x  = (const float*)d_in[0];
    const int*   ei = (const int*)d_in[1];
    const float* W1 = (const float*)d_in[2];
    const float* b1 = (const float*)d_in[3];
    const float* W2 = (const float*)d_in[4];
    const float* b2 = (const float*)d_in[5];
    const float* Wc = (const float*)d_in[6];
    const float* bc = (const float*)d_in[7];

    const int N = in_sizes[0] / FEAT;        // 100000
    const int E = in_sizes[1] / 2;           // 1600000
    const int C = out_size;                  // 32
    const int* srcI = ei;
    const int* dstI = ei + E;
    const int NC = (E + CHUNK - 1) / CHUNK;  // edge chunks (391, <= 512)
    const int NBK = (N + 255) >> 8;          // node buckets (391, <= MAXBUCK)
    const size_t csrCap = (size_t)E + (size_t)NBK * BPAD + 64;  // padded layout

    // workspace carve (256B aligned)
    auto align256 = [](size_t v) { return (v + 255) & ~(size_t)255; };
    char* w = (char*)d_ws;
    int*            cnt     = (int*)w;            w += align256((size_t)N * 4);
    float*          dinv    = (float*)w;          w += align256((size_t)N * 4);
    int*            cursor  = (int*)w;            w += align256((size_t)N * 4);
    int*            csr_src = (int*)w;            w += align256(csrCap * 4);
    int*            binned  = (int*)w;            w += align256((size_t)E * 4);
    int*            hist    = (int*)w;            w += align256((size_t)NBK * NC * 4);
    int*            hoff    = (int*)w;            w += align256((size_t)NBK * NC * 4);
    int*            btot    = (int*)w;            w += align256((size_t)NBK * 4);
    int*            bboff   = (int*)w;            w += align256((size_t)(NBK + 1) * 4);
    unsigned short* Wbf1    = (unsigned short*)w; w += align256((size_t)FEAT * FEAT * 2);
    unsigned short* Wbf2    = (unsigned short*)w; w += align256((size_t)FEAT * FEAT * 2);
    unsigned char*  gbuf    = (unsigned char*)w;  w += align256((size_t)(N + 1) * FEAT);
    unsigned char*  bufA    = (unsigned char*)w;  w += align256((size_t)N * FEAT);
    float*          partial = (float*)w;          w += align256((size_t)PBLK * FEAT * 4);

    // W pre-pack (both layers) + gbuf zero-row init
    wprep2<<<128, 256, 0, stream>>>(W1, W2, Wbf1, Wbf2, gbuf, N);

    // ---- atomic-free CSR build (all kernels >= 391 blocks except bscan) ----
    hist2<<<NC, 256, 0, stream>>>(dstI, hist, E, NC, NBK);
    rowsum_k<<<NBK, 256, 0, stream>>>(hist, btot, NC);
    bscan_k<<<1, 512, 0, stream>>>(btot, bboff, NBK);
    rowoff_k<<<NBK, 512, 0, stream>>>(hist, bboff, hoff, NC);
    fill2<<<NC, 256, 0, stream>>>(srcI, dstI, hoff, binned, E, NC, NBK);
    bucket_scat<<<NBK, 256, 0, stream>>>(binned, bboff, cnt, dinv, cursor, csr_src, N);

    const int gGemm = (N + 63) / 64;
    const int gAgg = (N + 3) / 4;

    // ---- layer 1 ----
    gemm_mfma<true><<<gGemm, 256, 0, stream>>>(x, Wbf1, dinv, gbuf, N);
    agg_csr<<<gAgg, 256, 0, stream>>>(cursor, cnt, csr_src, gbuf, dinv, b1,
                                      (unsigned short*)bufA, N);

    // ---- layer 2 ----
    gemm_mfma<false><<<gGemm, 256, 0, stream>>>(bufA, Wbf2, dinv, gbuf, N);
    agg_csr<<<gAgg, 256, 0, stream>>>(cursor, cnt, csr_src, gbuf, dinv, b2,
                                      (unsigned short*)bufA, N);

    // ---- pool + classifier ----
    pool_kernel<<<PBLK, 256, 0, stream>>>(bufA, partial, N);
    final_kernel<<<1, 128, 0, stream>>>(partial, Wc, bc, (float*)d_out, N, C);
}

// Round 10
// 267.387 us; speedup vs baseline: 2.2270x; 1.0447x over previous
//
#include <hip/hip_runtime.h>
#include <hip/hip_bf16.h>

// GCN: h1 = relu(Agg(x@W1)+b1); h2 = relu(Agg(h1@W2)+b2); out = mean(h2)@Wc + bc
// Agg via CSR gather; g = (X@W)*dinv stored OCP fp8 e4m3 (128B node-major rows,
// plus ONE ZERO ROW at index N for CSR padding).
// r10: PAIRED-NODE agg. Wave = 2 nodes (lanes 0-31 node A, 32-63 node B,
// 4 feats/lane); gather = dword x64 = 256B = 2 rows = 2 EDGES PER VMEM INSTR
// (was 1). bucket_scat pads each PAIR to common x16 length, round-interleaved
// (16 A-slots | 16 B-slots per round); pad -> zero row. Gather instrs/node
// 23.3 -> 13.5. Idx: each half-wave loads its own 16-idx block (4 int4 at
// base+half*64) - no selects. FETCH unchanged (lines/edge = 2 either way).
// r9: padded CSR (no tail masking), int4 idx loads, scalar bounds, pre-shifted
// entries. agg 48->~38us. [r8 inline-asm s_load aborted on HW - plain HIP only]
// r7: masked tail (48us). r6: pool atomic serialization fix (62->6us).
// r5: 32-bit byte-offset addressing (64->55us). r4: fp8 activations.
// r1-r3: plane-sharded L2-resident gather strictly worse (2x L2 transactions).
// NOTE: harness re-poisons 256MB workspace per iteration (~40us fill visible
// in rocprof) - untouchable; controllable budget ~= dur - 40us.
// CSR build atomic-free; ALL build kernels >= 391 blocks.
// GEMMs: mfma_f32_16x16x32_bf16, LDS-free, W pre-packed to k-block layout.

#define FEAT 128
#define CHUNK 4096      // edges per chunk (391 chunks)
#define MAXBUCK 512     // max node-buckets (N <= 131072); also NC cap
#define ECAP 12288      // LDS edge staging cap in bucket_scat (48 KB of int)
#define PBLK 512        // pool stage-1 blocks
#define BPAD 16384      // per-bucket padded-layout slack (pair padding, safe to deg<=72)

typedef __attribute__((ext_vector_type(8))) short short8;
typedef __attribute__((ext_vector_type(4))) float float4v;
typedef __attribute__((ext_vector_type(2))) float floatx2;

union I4S8 { int4 i; short8 s; };

static __device__ inline unsigned short f2bf(float f) {
    union { __hip_bfloat16 h; unsigned short u; } cv;
    cv.h = __float2bfloat16(f);
    return cv.u;
}

// ---- OCP fp8 e4m3 helpers ----
static __device__ inline floatx2 fp8x2_dec(unsigned int u) {
#if __has_builtin(__builtin_amdgcn_cvt_pk_f32_fp8)
    return __builtin_amdgcn_cvt_pk_f32_fp8((int)u, false);
#else
    floatx2 r;
    unsigned int b0 = u & 0xFFu, b1 = (u >> 8) & 0xFFu;
    r.x = __uint_as_float(((b0 & 0x80u) << 24) | ((b0 & 0x7Fu) << 20)) * 0x1p+120f;
    r.y = __uint_as_float(((b1 & 0x80u) << 24) | ((b1 & 0x7Fu) << 20)) * 0x1p+120f;
    return r;
#endif
}

static __device__ inline floatx2 fp8x2_dec_hi(unsigned int u) {
#if __has_builtin(__builtin_amdgcn_cvt_pk_f32_fp8)
    return __builtin_amdgcn_cvt_pk_f32_fp8((int)u, true);
#else
    return fp8x2_dec(u >> 16);
#endif
}

// pack two floats -> two fp8 e4m3 bytes (low word)
static __device__ inline unsigned short fp8x2_enc(float x, float y) {
#if __has_builtin(__builtin_amdgcn_cvt_pk_fp8_f32)
    return (unsigned short)(__builtin_amdgcn_cvt_pk_fp8_f32(x, y, 0, false) & 0xFFFF);
#else
    auto enc1 = [](float f) -> unsigned int {
        unsigned int u = __float_as_uint(f);
        unsigned int s = (u >> 24) & 0x80u;
        float a = fabsf(f);
        a = fminf(a, 448.0f);
        unsigned int code;
        if (a < 0.015625f) {
            code = (unsigned int)(int)rintf(a * 512.0f);
        } else {
            unsigned int au = __float_as_uint(a);
            unsigned int r = au + 0x0007FFFFu + ((au >> 20) & 1u);
            unsigned int e = (r >> 23) - 120u;
            unsigned int m = (r >> 20) & 7u;
            code = (e << 3) | m;
            if (code > 0x7Eu) code = 0x7Eu;
        }
        return code | s;
    };
    return (unsigned short)(enc1(x) | (enc1(y) << 8));
#endif
}

static __device__ inline unsigned char fp8enc(float f) {
#if __has_builtin(__builtin_amdgcn_cvt_pk_fp8_f32)
    return (unsigned char)(__builtin_amdgcn_cvt_pk_fp8_f32(f, 0.0f, 0, false) & 0xFF);
#else
    return (unsigned char)(fp8x2_enc(f, 0.0f) & 0xFF);
#endif
}

// ---- build phase 1: per-chunk histogram over node buckets (dst>>8) ----
__global__ __launch_bounds__(256) void hist2(const int* __restrict__ dst,
                                             int* __restrict__ hist,
                                             int nE, int NC, int nbuck) {
    __shared__ int h[MAXBUCK];
    int c = blockIdx.x, t = threadIdx.x;
    for (int i = t; i < nbuck; i += 256) h[i] = 0;
    __syncthreads();
    int beg = c * CHUNK, end = min(nE, beg + CHUNK);
    for (int e = beg + t; e < end; e += 256)
        atomicAdd(&h[dst[e] >> 8], 1);
    __syncthreads();
    for (int i = t; i < nbuck; i += 256) hist[i * NC + c] = h[i];
}

// ---- phase 2a: per-bucket totals (wide: one block per bucket) ----
__global__ __launch_bounds__(256) void rowsum_k(const int* __restrict__ hist,
                                                int* __restrict__ btot, int NC) {
    __shared__ int red[256];
    int b = blockIdx.x, t = threadIdx.x;
    int s = 0;
    for (int c = t; c < NC; c += 256) s += hist[b * NC + c];
    red[t] = s;
    __syncthreads();
    for (int o = 128; o > 0; o >>= 1) {
        if (t < o) red[t] += red[t + o];
        __syncthreads();
    }
    if (t == 0) btot[b] = red[0];
}

// ---- phase 2b: exclusive scan of bucket totals (nbuck <= 512) ----
__global__ __launch_bounds__(512) void bscan_k(const int* __restrict__ btot,
                                               int* __restrict__ bboff, int nbuck) {
    __shared__ int sc[512];
    int t = threadIdx.x;
    int v = (t < nbuck) ? btot[t] : 0;
    sc[t] = v;
    __syncthreads();
    for (int o = 1; o < 512; o <<= 1) {
        int add = (t >= o) ? sc[t - o] : 0;
        __syncthreads();
        sc[t] += add;
        __syncthreads();
    }
    if (t < nbuck) {
        bboff[t] = sc[t] - v;
        if (t == nbuck - 1) bboff[nbuck] = sc[t];
    }
}

// ---- phase 2c: per-(bucket,chunk) offsets (wide: block-parallel scan, NC<=512) ----
__global__ __launch_bounds__(512) void rowoff_k(const int* __restrict__ hist,
                                                const int* __restrict__ bboff,
                                                int* __restrict__ hoff, int NC) {
    __shared__ int sc[512];
    int b = blockIdx.x, t = threadIdx.x;
    int v = (t < NC) ? hist[b * NC + t] : 0;
    sc[t] = v;
    __syncthreads();
    for (int o = 1; o < 512; o <<= 1) {
        int add = (t >= o) ? sc[t - o] : 0;
        __syncthreads();
        sc[t] += add;
        __syncthreads();
    }
    if (t < NC) hoff[b * NC + t] = bboff[b] + sc[t] - v;
}

// ---- phase 3: pack (src<<8|dloc) bucket-grouped; LDS cursors ----
__global__ __launch_bounds__(256) void fill2(const int* __restrict__ src,
                                             const int* __restrict__ dst,
                                             const int* __restrict__ off,
                                             int* __restrict__ binned,
                                             int nE, int NC, int nbuck) {
    __shared__ int cur[MAXBUCK];
    int c = blockIdx.x, t = threadIdx.x;
    for (int i = t; i < nbuck; i += 256) cur[i] = off[i * NC + c];
    __syncthreads();
    int beg = c * CHUNK, end = min(nE, beg + CHUNK);
    for (int e = beg + t; e < end; e += 256) {
        int d = dst[e];
        int pos = atomicAdd(&cur[d >> 8], 1);
        binned[pos] = (src[e] << 8) | (d & 255);
    }
}

// ---- phase 4: per-bucket count + dinv + cursor + PAIR-PADDED csr scatter ----
// Pair p = nodes (2p, 2p+1). pairLen = ceil(max(dA,dB)/16)*16; pair region =
// 2*pairLen slots, round-interleaved: round r = [A slots 16r..] then [B slots].
// Node (p,h) slot q -> poff[p] + (q>>4)*32 + h*16 + (q&15). Pad -> zero row.
// cnt[node] = pairLen (agg loop bound); csr entries PRE-SHIFTED (src<<7).
__global__ __launch_bounds__(256) void bucket_scat(const int* __restrict__ binned,
                                                   const int* __restrict__ bboff,
                                                   int* __restrict__ cnt,
                                                   float* __restrict__ dinv,
                                                   int* __restrict__ cursor,
                                                   int* __restrict__ csr_src, int n) {
    __shared__ int se[ECAP];
    __shared__ int lcnt[256];
    __shared__ int lcur[256];
    __shared__ int ssc[256];
    __shared__ int poff[128];
    int b = blockIdx.x, t = threadIdx.x;
    int node0 = b << 8;
    int nloc = min(256, n - node0);
    int ebeg = bboff[b], eend = bboff[b + 1];
    int ne = eend - ebeg;
    int pbase = (ebeg + b * BPAD + 15) & ~15;   // 16-aligned padded bucket base
    int zOff = n << 7;                          // zero-row byte offset
    lcnt[t] = 0;
    lcur[t] = 0;
    __syncthreads();
    bool staged = (ne <= ECAP);
    if (staged) {
        for (int i = t; i < ne; i += 256) {
            int e = binned[ebeg + i];
            se[i] = e;
            atomicAdd(&lcnt[e & 255], 1);
        }
    } else {
        for (int i = t; i < ne; i += 256)
            atomicAdd(&lcnt[binned[ebeg + i] & 255], 1);
    }
    __syncthreads();
    int myc = (t < nloc) ? lcnt[t] : 0;
    // pair slot totals (thread t<128 owns pair t)
    int npair = (nloc + 1) >> 1;
    int pairSlots = 0;
    if (t < npair) {
        int mx = max(lcnt[2 * t], lcnt[2 * t + 1]);
        pairSlots = 2 * ((mx + 15) & ~15);
    }
    ssc[t] = pairSlots;
    __syncthreads();
    for (int o = 1; o < 256; o <<= 1) {
        int add = (t >= o) ? ssc[t - o] : 0;
        __syncthreads();
        ssc[t] += add;
        __syncthreads();
    }
    if (t < npair) poff[t] = ssc[t] - pairSlots;   // exclusive pair offset
    __syncthreads();
    if (t < nloc) {
        int p = t >> 1;
        int pl = ((max(lcnt[p * 2], lcnt[p * 2 + 1]) + 15) & ~15);
        cnt[node0 + t] = pl;                       // pairLen (rounds*16)
        dinv[node0 + t] = rsqrtf((float)(myc + 1));
        cursor[node0 + t] = pbase + poff[p];       // pair base (slot units)
    }
    __syncthreads();
    if (staged) {
        for (int i = t; i < ne; i += 256) {
            int e = se[i];
            int loc = e & 255;
            int q = atomicAdd(&lcur[loc], 1);
            int slot = pbase + poff[loc >> 1] + ((q >> 4) << 5) + ((loc & 1) << 4) + (q & 15);
            csr_src[slot] = (int)(((unsigned int)e >> 8) << 7);
        }
    } else {
        for (int i = t; i < ne; i += 256) {
            int e = binned[ebeg + i];
            int loc = e & 255;
            int q = atomicAdd(&lcur[loc], 1);
            int slot = pbase + poff[loc >> 1] + ((q >> 4) << 5) + ((loc & 1) << 4) + (q & 15);
            csr_src[slot] = (int)(((unsigned int)e >> 8) << 7);
        }
    }
    // pad fill (covers missing partner of an odd last node too)
    int nlocp = (nloc + 1) & ~1;
    if (t < nlocp) {
        int p = t >> 1, h = t & 1;
        int pl = ((max(lcnt[p * 2], lcnt[p * 2 + 1]) + 15) & ~15);
        int base = pbase + poff[p] + (h << 4);
        for (int q = myc; q < pl; q++)
            csr_src[base + ((q >> 4) << 5) + (q & 15)] = zOff;
    }
}

// ---- W pre-pack (both layers) + gbuf zero-row init ----
__global__ __launch_bounds__(256) void wprep2(const float* __restrict__ W1,
                                              const float* __restrict__ W2,
                                              unsigned short* __restrict__ Wbf1,
                                              unsigned short* __restrict__ Wbf2,
                                              unsigned char* __restrict__ gbuf,
                                              int n) {
    int tid = blockIdx.x * 256 + threadIdx.x;   // 32768 threads
    if (tid < 32)
        ((unsigned int*)(gbuf + (size_t)n * FEAT))[tid] = 0u;  // zero row N
    const float* W = (tid < 16384) ? W1 : W2;
    unsigned short* O = (tid < 16384) ? Wbf1 : Wbf2;
    int id = tid & 16383;
    int chunk = id >> 3, j = id & 7;
    int kb = chunk >> 7, nn = chunk & 127;
    O[id] = f2bf(W[(kb * 8 + j) * FEAT + nn]);
}

// ---- MFMA GEMM: gout[N][128](fp8) = bf16(X) @ Wbf * dinv[row] ----
// AFP32=true: X is fp32 rows. AFP32=false: X is fp8 e4m3 rows (exact->bf16).
template <bool AFP32>
__global__ __launch_bounds__(256) void gemm_mfma(const void* __restrict__ Xv,
                                                 const unsigned short* __restrict__ Wbf,
                                                 const float* __restrict__ dinv,
                                                 unsigned char* __restrict__ gout,
                                                 int n) {
    int wave = threadIdx.x >> 6, lane = threadIdx.x & 63;
    int m0 = blockIdx.x * 64 + wave * 16;
    if (m0 >= n) return;
    int col = lane & 15, quad = lane >> 4;
    int mc = min(m0 + col, n - 1);

    short8 afr[4];
    if (AFP32) {
        const float* X = (const float*)Xv;
        const float* xr = X + (size_t)mc * FEAT + quad * 8;
#pragma unroll
        for (int ks = 0; ks < 4; ks++) {
            float4 lo = *(const float4*)(xr + ks * 32);
            float4 hi = *(const float4*)(xr + ks * 32 + 4);
            short8 a;
            a[0] = (short)f2bf(lo.x); a[1] = (short)f2bf(lo.y);
            a[2] = (short)f2bf(lo.z); a[3] = (short)f2bf(lo.w);
            a[4] = (short)f2bf(hi.x); a[5] = (short)f2bf(hi.y);
            a[6] = (short)f2bf(hi.z); a[7] = (short)f2bf(hi.w);
            afr[ks] = a;
        }
    } else {
        const unsigned char* X8 = (const unsigned char*)Xv;
        const unsigned char* xr = X8 + (size_t)mc * FEAT + quad * 8;
#pragma unroll
        for (int ks = 0; ks < 4; ks++) {
            uint2 u2 = *(const uint2*)(xr + ks * 32);
            floatx2 p0 = fp8x2_dec(u2.x);
            floatx2 p1 = fp8x2_dec_hi(u2.x);
            floatx2 p2 = fp8x2_dec(u2.y);
            floatx2 p3 = fp8x2_dec_hi(u2.y);
            short8 a;
            a[0] = (short)f2bf(p0.x); a[1] = (short)f2bf(p0.y);
            a[2] = (short)f2bf(p1.x); a[3] = (short)f2bf(p1.y);
            a[4] = (short)f2bf(p2.x); a[5] = (short)f2bf(p2.y);
            a[6] = (short)f2bf(p3.x); a[7] = (short)f2bf(p3.y);
            afr[ks] = a;
        }
    }

    float dvr[4];
#pragma unroll
    for (int r = 0; r < 4; r++)
        dvr[r] = dinv[min(m0 + quad * 4 + r, n - 1)];

    const int4* Wb = (const int4*)Wbf;
#pragma unroll
    for (int nt = 0; nt < 8; nt++) {
        float4v acc = {0.f, 0.f, 0.f, 0.f};
#pragma unroll
        for (int ks = 0; ks < 4; ks++) {
            int kb = ks * 4 + quad;
            I4S8 u; u.i = Wb[kb * FEAT + nt * 16 + col];
            acc = __builtin_amdgcn_mfma_f32_16x16x32_bf16(afr[ks], u.s, acc, 0, 0, 0);
        }
#pragma unroll
        for (int r = 0; r < 4; r++) {
            int row = m0 + quad * 4 + r;
            if (row < n)
                gout[(size_t)row * FEAT + nt * 16 + col] = fp8enc(acc[r] * dvr[r]);
        }
    }
}

// ---- agg: PAIRED CSR gather + bias + relu -> fp8 rows (2 nodes per wave) ----
// lanes 0-31 = node A, 32-63 = node B; each lane owns 4 feats (1 dword).
// Gather instr = dword x64 = 2 rows = 2 edges. Idx: each half loads its own
// 16-idx block (4 int4 at pairBase + r*128 + half*64). Rounds = pairLen/16.
__global__ __launch_bounds__(256) void agg_csr(const int* __restrict__ cursor,
                                               const int* __restrict__ cnt,
                                               const int* __restrict__ csr_src,
                                               const unsigned char* __restrict__ gbuf,
                                               const float* __restrict__ dinv,
                                               const float* __restrict__ bias,
                                               unsigned char* __restrict__ outb,
                                               int n) {
    int pair = blockIdx.x * 4 + (threadIdx.x >> 6);
    int nodeA = pair << 1;
    if (nodeA >= n) return;
    unsigned lane = threadIdx.x & 63;
    unsigned half = lane >> 5;                  // 0 = A, 1 = B
    unsigned sub = lane & 31;
    int node = nodeA + (int)half;               // n even -> node < n
    unsigned fb = sub << 2;                     // 4B feature offset in row

    int curS = __builtin_amdgcn_readfirstlane(cursor[nodeA]);  // pair base (slots)
    int plS = __builtin_amdgcn_readfirstlane(cnt[nodeA]);      // pairLen
    const unsigned char* csrB = (const unsigned char*)csr_src;
    const unsigned char* ip0 = csrB + (((size_t)(unsigned)curS) << 2) + (half << 6);

    unsigned su = *(const unsigned*)(gbuf + ((((unsigned)node) << 7) | fb));
    floatx2 a01 = fp8x2_dec(su), a23 = fp8x2_dec_hi(su);       // self-loop
    floatx2 b01 = {0.f, 0.f}, b23 = {0.f, 0.f};

    int rounds = plS >> 4;
    for (int r = 0; r < rounds; r++) {
        const unsigned char* p = ip0 + ((size_t)(unsigned)r << 7);
        int4 w0 = *(const int4*)(p);
        int4 w1 = *(const int4*)(p + 16);
        int4 w2 = *(const int4*)(p + 32);
        int4 w3 = *(const int4*)(p + 48);
        unsigned uu[16];
        uu[0]  = *(const unsigned*)(gbuf + ((unsigned)w0.x | fb));
        uu[1]  = *(const unsigned*)(gbuf + ((unsigned)w0.y | fb));
        uu[2]  = *(const unsigned*)(gbuf + ((unsigned)w0.z | fb));
        uu[3]  = *(const unsigned*)(gbuf + ((unsigned)w0.w | fb));
        uu[4]  = *(const unsigned*)(gbuf + ((unsigned)w1.x | fb));
        uu[5]  = *(const unsigned*)(gbuf + ((unsigned)w1.y | fb));
        uu[6]  = *(const unsigned*)(gbuf + ((unsigned)w1.z | fb));
        uu[7]  = *(const unsigned*)(gbuf + ((unsigned)w1.w | fb));
        uu[8]  = *(const unsigned*)(gbuf + ((unsigned)w2.x | fb));
        uu[9]  = *(const unsigned*)(gbuf + ((unsigned)w2.y | fb));
        uu[10] = *(const unsigned*)(gbuf + ((unsigned)w2.z | fb));
        uu[11] = *(const unsigned*)(gbuf + ((unsigned)w2.w | fb));
        uu[12] = *(const unsigned*)(gbuf + ((unsigned)w3.x | fb));
        uu[13] = *(const unsigned*)(gbuf + ((unsigned)w3.y | fb));
        uu[14] = *(const unsigned*)(gbuf + ((unsigned)w3.z | fb));
        uu[15] = *(const unsigned*)(gbuf + ((unsigned)w3.w | fb));
#pragma unroll
        for (int k = 0; k < 16; k += 2) {
            a01 += fp8x2_dec(uu[k]);
            a23 += fp8x2_dec_hi(uu[k]);
            b01 += fp8x2_dec(uu[k + 1]);
            b23 += fp8x2_dec_hi(uu[k + 1]);
        }
    }
    a01 += b01;
    a23 += b23;
    float dv = dinv[node];
    float4 bv = ((const float4*)bias)[sub];
    float r0 = fmaxf(a01.x * dv + bv.x, 0.0f);
    float r1 = fmaxf(a01.y * dv + bv.y, 0.0f);
    float r2 = fmaxf(a23.x * dv + bv.z, 0.0f);
    float r3 = fmaxf(a23.y * dv + bv.w, 0.0f);
    unsigned outw = (unsigned)fp8x2_enc(r0, r1) | ((unsigned)fp8x2_enc(r2, r3) << 16);
    *(unsigned*)(outb + ((((unsigned)node) << 7) | fb)) = outw;
}

// ---- mean pool stage 1: per-block partial sums, NO global atomics ----
__global__ __launch_bounds__(256) void pool_kernel(const unsigned char* __restrict__ a,
                                                   float* __restrict__ partial, int n) {
    __shared__ float red[16][132];   // +4 pad
    int t = threadIdx.x, b = blockIdx.x;
    int fg = t & 15;
    int rg = t >> 4;
    unsigned fb = (unsigned)fg << 3;             // feature byte offset
    floatx2 s01 = {0.f, 0.f}, s23 = {0.f, 0.f}, s45 = {0.f, 0.f}, s67 = {0.f, 0.f};
    for (int i = (b << 4) | rg; i < n; i += PBLK * 16) {
        uint2 u2 = *(const uint2*)(a + (((unsigned)i << 7) | fb));
        s01 += fp8x2_dec(u2.x);
        s23 += fp8x2_dec_hi(u2.x);
        s45 += fp8x2_dec(u2.y);
        s67 += fp8x2_dec_hi(u2.y);
    }
    red[rg][fb + 0] = s01.x; red[rg][fb + 1] = s01.y;
    red[rg][fb + 2] = s23.x; red[rg][fb + 3] = s23.y;
    red[rg][fb + 4] = s45.x; red[rg][fb + 5] = s45.y;
    red[rg][fb + 6] = s67.x; red[rg][fb + 7] = s67.y;
    __syncthreads();
    if (t < FEAT) {
        float s = 0.0f;
#pragma unroll
        for (int k = 0; k < 16; k++) s += red[k][t];
        partial[b * FEAT + t] = s;
    }
}

// ---- final: reduce partials; out[c] = (pooled/N) . Wc[:,c] + bc[c] ----
__global__ __launch_bounds__(128) void final_kernel(const float* __restrict__ partial,
                                                    const float* __restrict__ Wc,
                                                    const float* __restrict__ bc,
                                                    float* __restrict__ out,
                                                    int n, int C) {
    __shared__ float p[FEAT];
    int t = threadIdx.x;
    float s = 0.0f;
    for (int b = 0; b < PBLK; b++) s += partial[b * FEAT + t];
    p[t] = s * (1.0f / (float)n);
    __syncthreads();
    if (t < C) {
        float acc = bc[t];
        for (int h = 0; h < FEAT; h++)
            acc += p[h] * Wc[h * C + t];
        out[t] = acc;
    }
}

extern "C" void kernel_launch(void* const* d_in, const int* in_sizes, int n_in,
                              void* d_out, int out_size, void* d_ws, size_t ws_size,
                              hipStream_t stream) {
    const float* x  = (const float*)d_in[0];
    const int*   ei = (const int*)d_in[1];
    const float* W1 = (const float*)d_in[2];
    const float* b1 = (const float*)d_in[3];
    const float* W2 = (const float*)d_in[4];
    const float* b2 = (const float*)d_in[5];
    const float* Wc = (const float*)d_in[6];
    const float* bc = (const float*)d_in[7];

    const int N = in_sizes[0] / FEAT;        // 100000
    const int E = in_sizes[1] / 2;           // 1600000
    const int C = out_size;                  // 32
    const int* srcI = ei;
    const int* dstI = ei + E;
    const int NC = (E + CHUNK - 1) / CHUNK;  // edge chunks (391, <= 512)
    const int NBK = (N + 255) >> 8;          // node buckets (391, <= MAXBUCK)
    const size_t csrCap = (size_t)E + (size_t)NBK * BPAD + 64;  // padded layout

    // workspace carve (256B aligned)
    auto align256 = [](size_t v) { return (v + 255) & ~(size_t)255; };
    char* w = (char*)d_ws;
    int*            cnt     = (int*)w;            w += align256((size_t)N * 4);
    float*          dinv    = (float*)w;          w += align256((size_t)N * 4);
    int*            cursor  = (int*)w;            w += align256((size_t)N * 4);
    int*            csr_src = (int*)w;            w += align256(csrCap * 4);
    int*            binned  = (int*)w;            w += align256((size_t)E * 4);
    int*            hist    = (int*)w;            w += align256((size_t)NBK * NC * 4);
    int*            hoff    = (int*)w;            w += align256((size_t)NBK * NC * 4);
    int*            btot    = (int*)w;            w += align256((size_t)NBK * 4);
    int*            bboff   = (int*)w;            w += align256((size_t)(NBK + 1) * 4);
    unsigned short* Wbf1    = (unsigned short*)w; w += align256((size_t)FEAT * FEAT * 2);
    unsigned short* Wbf2    = (unsigned short*)w; w += align256((size_t)FEAT * FEAT * 2);
    unsigned char*  gbuf    = (unsigned char*)w;  w += align256((size_t)(N + 1) * FEAT);
    unsigned char*  bufA    = (unsigned char*)w;  w += align256((size_t)N * FEAT);
    float*          partial = (float*)w;          w += align256((size_t)PBLK * FEAT * 4);

    // W pre-pack (both layers) + gbuf zero-row init
    wprep2<<<128, 256, 0, stream>>>(W1, W2, Wbf1, Wbf2, gbuf, N);

    // ---- atomic-free CSR build (all kernels >= 391 blocks except bscan) ----
    hist2<<<NC, 256, 0, stream>>>(dstI, hist, E, NC, NBK);
    rowsum_k<<<NBK, 256, 0, stream>>>(hist, btot, NC);
    bscan_k<<<1, 512, 0, stream>>>(btot, bboff, NBK);
    rowoff_k<<<NBK, 512, 0, stream>>>(hist, bboff, hoff, NC);
    fill2<<<NC, 256, 0, stream>>>(srcI, dstI, hoff, binned, E, NC, NBK);
    bucket_scat<<<NBK, 256, 0, stream>>>(binned, bboff, cnt, dinv, cursor, csr_src, N);

    const int gGemm = (N + 63) / 64;
    const int gAgg = (N + 7) / 8;            // 4 pairs (8 nodes) per block

    // ---- layer 1 ----
    gemm_mfma<true><<<gGemm, 256, 0, stream>>>(x, Wbf1, dinv, gbuf, N);
    agg_csr<<<gAgg, 256, 0, stream>>>(cursor, cnt, csr_src, gbuf, dinv, b1,
                                      bufA, N);

    // ---- layer 2 ----
    gemm_mfma<false><<<gGemm, 256, 0, stream>>>(bufA, Wbf2, dinv, gbuf, N);
    agg_csr<<<gAgg, 256, 0, stream>>>(cursor, cnt, csr_src, gbuf, dinv, b2,
                                      bufA, N);

    // ---- pool + classifier ----
    pool_kernel<<<PBLK, 256, 0, stream>>>(bufA, partial, N);
    final_kernel<<<1, 128, 0, stream>>>(partial, Wc, bc, (float*)d_out, N, C);
}